// Round 3
// baseline (625.218 us; speedup 1.0000x reference)
//
#include <hip/hip_runtime.h>

typedef unsigned short u16;
typedef unsigned int u32;
typedef short short8 __attribute__((ext_vector_type(8)));
typedef float f32x4 __attribute__((ext_vector_type(4)));

#define NB 64
#define NFB 257
#define NANG 360

__device__ __forceinline__ u16 f2bf(float x) {
    u32 u = __float_as_uint(x);
    u = (u + 0x7fffu + ((u >> 16) & 1u)) >> 16;
    return (u16)u;
}
__device__ __forceinline__ float bf2f(u16 h) { return __uint_as_float(((u32)h) << 16); }

// ---------------------------------------------------------------------------
// BN fold: scale = g*rsqrt(v+eps), bias = b - m*scale.  4 layers, 1 launch.
// ---------------------------------------------------------------------------
__global__ __launch_bounds__(256) void bnprep(
    const float* g1, const float* b1, const float* m1, const float* v1,
    const float* g2, const float* b2, const float* m2, const float* v2,
    const float* g3, const float* b3, const float* m3, const float* v3,
    const float* g4, const float* b4, const float* m4, const float* v4,
    float* out)
{
    int L = blockIdx.x;
    const float* gs[4] = {g1, g2, g3, g4};
    const float* bs[4] = {b1, b2, b3, b4};
    const float* ms[4] = {m1, m2, m3, m4};
    const float* vs[4] = {v1, v2, v3, v4};
    int n = (L == 3) ? 257 : 64;
    float* sc = out + L * 1024;
    float* bi = sc + 512;
    for (int i = threadIdx.x; i < n; i += 256) {
        float s = gs[L][i] * rsqrtf(vs[L][i] + 1e-5f);
        sc[i] = s;
        bi[i] = bs[L][i] - ms[L][i] * s;
    }
}

// ---------------------------------------------------------------------------
// Weight pack (generic): Bp[(chunk*2+h)*NFTOT + nf][lane][8] bf16,
// chunk = s*KCC + kc.  lane l: k = kc*32 + (l>>4)*8 + e, n = nf*16 + (l&15).
// w layout: w[(n*CREAL + k)*NT + s].
// ---------------------------------------------------------------------------
__global__ __launch_bounds__(256) void bpack(
    const float* __restrict__ w, u16* __restrict__ Bp,
    int CREAL, int OCREAL, int NT, int KCC, int NFTOT)
{
    int i = blockIdx.x * 256 + threadIdx.x;
    int total = NT * KCC * 2 * NFTOT * 64;
    if (i >= total) return;
    int lane = i & 63;
    int t = i >> 6;
    int nf = t % NFTOT;
    int th = t / NFTOT;
    int h = th & 1;
    int chunk = th >> 1;
    int s = chunk / KCC, kc = chunk % KCC;
    int n = nf * 16 + (lane & 15);
    int k0 = kc * 32 + (lane >> 4) * 8;
    u16 o8[8];
    #pragma unroll
    for (int e = 0; e < 8; ++e) {
        int k = k0 + e;
        float v = 0.f;
        if (k < CREAL && n < OCREAL) v = w[((size_t)n * CREAL + k) * NT + s];
        u16 hh = f2bf(v);
        o8[e] = (h == 0) ? hh : f2bf(v - bf2f(hh));
    }
    u16* d = Bp + (size_t)i * 8;
    #pragma unroll
    for (int e = 0; e < 8; ++e) d[e] = o8[e];
}

// ---------------------------------------------------------------------------
// Weight pack for conv1 (C=8, K = 4 pixels x 8 ch; kx=q in 0..3, kx=3 zero).
// chunk = ky (0..2).  lane l: q=l>>4 -> kx, e -> channel, n = nf*16+(l&15).
// conv1 w OIHW (64,8,3,3): w[((n*8+e)*3+ky)*3+q]
// ---------------------------------------------------------------------------
__global__ __launch_bounds__(256) void bpack1(const float* __restrict__ w, u16* __restrict__ Bp)
{
    int i = blockIdx.x * 256 + threadIdx.x;
    if (i >= 3 * 2 * 4 * 64) return;
    int lane = i & 63;
    int t = i >> 6;
    int nf = t % 4;
    int th = t / 4;
    int h = th & 1;
    int ky = th >> 1;
    int n = nf * 16 + (lane & 15);
    int q = lane >> 4;
    u16 o8[8];
    #pragma unroll
    for (int e = 0; e < 8; ++e) {
        float v = (q < 3) ? w[((size_t)(n * 8 + e) * 3 + ky) * 3 + q] : 0.f;
        u16 hh = f2bf(v);
        o8[e] = (h == 0) ? hh : f2bf(v - bf2f(hh));
    }
    u16* d = Bp + (size_t)i * 8;
    #pragma unroll
    for (int e = 0; e < 8; ++e) d[e] = o8[e];
}

// ---------------------------------------------------------------------------
// X (64,8,128,128) f32 NCHW -> padded NHWC bf16 hi/lo (b,130,130,8).
// LDS transpose; vectorized 16B stores.
// ---------------------------------------------------------------------------
__global__ __launch_bounds__(256) void xpack_kernel(
    const float* __restrict__ X, u16* __restrict__ hi, u16* __restrict__ lo)
{
    __shared__ float Xs[8][132];
    int bid = blockIdx.x;
    int prow = bid % 130;
    int b = bid / 130;
    bool inr = (prow >= 1 && prow <= 128);
    for (int i = threadIdx.x; i < 8 * 130; i += 256) {
        int c = i / 130, pcol = i % 130;
        float v = 0.f;
        if (inr && pcol >= 1 && pcol <= 128)
            v = X[(((size_t)b * 8 + c) * 128 + (prow - 1)) * 128 + (pcol - 1)];
        Xs[c][pcol] = v;
    }
    __syncthreads();
    for (int p = threadIdx.x; p < 130; p += 256) {
        short8 h8, l8;
        #pragma unroll
        for (int c = 0; c < 8; ++c) {
            float f = Xs[c][p];
            u16 hh = f2bf(f);
            h8[c] = (short)hh;
            l8[c] = (short)f2bf(f - bf2f(hh));
        }
        size_t o = (((size_t)b * 130 + prow) * 130 + p) * 8;
        *(short8*)(hi + o) = h8;
        *(short8*)(lo + o) = l8;
    }
}

// ---------------------------------------------------------------------------
// Zero the padding border of a padded-NHWC bf16 hi/lo pair.
// ---------------------------------------------------------------------------
__global__ __launch_bounds__(256) void zpad(
    u16* hi, u16* lo, int Bn, int Hp, int Wp, int Cb, int doCols)
{
    int perB = 2 * Wp + (doCols ? 2 * (Hp - 2) : 0);
    long total = (long)Bn * perB * Cb;
    for (long idx = blockIdx.x * 256L + threadIdx.x; idx < total; idx += (long)gridDim.x * 256) {
        int c = (int)(idx % Cb);
        long t = idx / Cb;
        int p = (int)(t % perB);
        int b = (int)(t / perB);
        int row, col;
        if (p < Wp) { row = 0; col = p; }
        else if (p < 2 * Wp) { row = Hp - 1; col = p - Wp; }
        else { int pp = p - 2 * Wp; row = 1 + (pp >> 1); col = (pp & 1) ? (Wp - 1) : 0; }
        size_t o = (((size_t)b * Hp + row) * Wp + col) * Cb + c;
        hi[o] = 0;
        lo[o] = 0;
    }
}

// ---------------------------------------------------------------------------
// conv1 dedicated: C=8, K packs 4 pixels x 8 ch (kx in K).  3 chunks only.
// BN+ReLU+pool2 -> padded NHWC bf16 hi/lo (b,66,66,64).
// ---------------------------------------------------------------------------
__global__ __launch_bounds__(256) void conv_c1(
    const u16* __restrict__ Ahi, const u16* __restrict__ Alo,
    const u16* __restrict__ Bp,
    const float* __restrict__ esc, const float* __restrict__ ebi,
    u16* __restrict__ Ohi, u16* __restrict__ Olo)
{
    constexpr int W = 128, Wst = 130, Hp = 130;
    constexpr int SROWS = 5;                 // R + KH - 1 + 1 (q-overflow guard row)
    constexpr int SPIX = SROWS * Wst;        // 650
    constexpr int PSTR = 48;                 // 16B data + 32B pad -> good bank spread
    constexpr int STAGEB = SPIX * PSTR;      // 31200
    constexpr int POOLB = 2 * 128 * 64 * 4;  // 65536 (R*W*OCB*4)
    __shared__ __align__(16) char sm[POOLB + 64];   // 2*STAGEB=62400 < POOLB

    int bid = blockIdx.x;
    int ytile = bid % 64;
    int b = bid / 64;
    int y0 = ytile * 2;
    int tid = threadIdx.x;
    int wv = tid >> 6;
    int l = tid & 63;
    int r = l & 15, q = l >> 4;

    // stage 5 padded rows (hi, lo), 16B per pixel
    for (int pix = tid; pix < SPIX; pix += 256) {
        int prow = y0 + pix / Wst, pcol = pix % Wst;
        uint4 vh = {0, 0, 0, 0}, vl = {0, 0, 0, 0};
        if (prow < Hp) {
            size_t g = (((size_t)b * Hp + prow) * Wst + pcol) * 16;
            vh = *(const uint4*)((const char*)Ahi + g);
            vl = *(const uint4*)((const char*)Alo + g);
        }
        *(uint4*)(sm + pix * PSTR) = vh;
        *(uint4*)(sm + STAGEB + pix * PSTR) = vl;
    }
    __syncthreads();

    f32x4 acc[4][4];
    #pragma unroll
    for (int mi = 0; mi < 4; ++mi)
        #pragma unroll
        for (int ni = 0; ni < 4; ++ni)
            acc[mi][ni] = (f32x4){0.f, 0.f, 0.f, 0.f};

    #pragma unroll
    for (int ky = 0; ky < 3; ++ky) {
        short8 ah[4], al[4];
        #pragma unroll
        for (int mi = 0; mi < 4; ++mi) {
            int mp0 = (wv * 4 + mi) * 16;
            int mpix = ((mp0 >> 7) + ky) * Wst + (mp0 & 127);
            int off = (mpix + r + q) * PSTR;
            ah[mi] = *(const short8*)(sm + off);
            al[mi] = *(const short8*)(sm + STAGEB + off);
        }
        #pragma unroll
        for (int ni = 0; ni < 4; ++ni) {
            const u16* bt = Bp + ((size_t)(ky * 2) * 4 + ni) * 512 + l * 8;
            short8 bh = *(const short8*)bt;
            short8 bl = *(const short8*)(bt + 4 * 512);
            #pragma unroll
            for (int mi = 0; mi < 4; ++mi) {
                acc[mi][ni] = __builtin_amdgcn_mfma_f32_16x16x32_bf16(ah[mi], bh, acc[mi][ni], 0, 0, 0);
                acc[mi][ni] = __builtin_amdgcn_mfma_f32_16x16x32_bf16(ah[mi], bl, acc[mi][ni], 0, 0, 0);
                acc[mi][ni] = __builtin_amdgcn_mfma_f32_16x16x32_bf16(al[mi], bh, acc[mi][ni], 0, 0, 0);
            }
        }
    }

    __syncthreads();
    float* pt = (float*)sm;
    #pragma unroll
    for (int mi = 0; mi < 4; ++mi)
        #pragma unroll
        for (int ni = 0; ni < 4; ++ni)
            #pragma unroll
            for (int j = 0; j < 4; ++j) {
                int mp = (wv * 4 + mi) * 16 + q * 4 + j;
                pt[mp * 64 + ni * 16 + r] = acc[mi][ni][j];
            }
    __syncthreads();
    for (int i = tid; i < 64 * 64; i += 256) {
        int c = i % 64;
        int x2 = i / 64;
        float sc0 = esc[c], bi0 = ebi[c];
        float m = -3.4e38f;
        #pragma unroll
        for (int dy = 0; dy < 2; ++dy)
            #pragma unroll
            for (int dx = 0; dx < 2; ++dx) {
                float v = fmaf(pt[(dy * 128 + 2 * x2 + dx) * 64 + c], sc0, bi0);
                m = fmaxf(m, v);
            }
        m = fmaxf(m, 0.f);
        size_t o = (((size_t)b * 66 + (y0 / 2 + 1)) * 66 + (x2 + 1)) * 64 + c;
        u16 hh = f2bf(m);
        Ohi[o] = hh;
        Olo[o] = f2bf(m - bf2f(hh));
    }
}

// ---------------------------------------------------------------------------
// Shift-GEMM conv via MFMA bf16 split (3 products), channel-sectioned staging.
// OUTMODE 0: BN+ReLU+pool2 -> padded NHWC bf16 hi/lo
// OUTMODE 1: BN+ReLU+pool2 -> f32 NHWC
// OUTMODE 2: +bias, leaky_relu(0.1) -> f32 (1D conv, W=1)
// ---------------------------------------------------------------------------
template<int C, int H, int W, int OC, int R, int KH, int KW, int NF, int MFW,
         int PSTR, int OUTMODE, int NFTOT, int CSECT>
__global__ __launch_bounds__(256) void conv_gemm(
    const u16* __restrict__ Ahi, const u16* __restrict__ Alo,
    const u16* __restrict__ Bp,
    const float* __restrict__ esc, const float* __restrict__ ebi,
    u16* __restrict__ Ohi, u16* __restrict__ Olo, float* __restrict__ Of)
{
    constexpr int KCC = (C + 31) / 32;
    constexpr int KCS = KCC / CSECT;
    constexpr int SECB = (C / CSECT) * 2;    // bytes per pixel per section
    constexpr int CB16 = SECB / 16;
    constexpr int Wst = W + KW - 1;
    constexpr int Hp = H + KH - 1;
    constexpr int SROWS = R + KH - 1;
    constexpr int SPIX = SROWS * Wst;
    constexpr int OCB = NF * 16;
    constexpr int HT = (H + R - 1) / R;
    constexpr int STAGEB = SPIX * PSTR;
    constexpr int POOLB = (OUTMODE == 2) ? 0 : (R * W * OCB * 4);
    constexpr int SMEMB = (2 * STAGEB > POOLB) ? (2 * STAGEB) : POOLB;
    __shared__ __align__(16) char sm[SMEMB + 64];

    int bid = blockIdx.x;
    int ytile = bid % HT;
    int b = bid / HT;
    int tid = threadIdx.x;
    int wv = tid >> 6;
    int l = tid & 63;
    int r = l & 15, q = l >> 4;
    int y0 = ytile * R;

    f32x4 acc[MFW][NF];
    #pragma unroll
    for (int mi = 0; mi < MFW; ++mi)
        #pragma unroll
        for (int ni = 0; ni < NF; ++ni)
            acc[mi][ni] = (f32x4){0.f, 0.f, 0.f, 0.f};

    for (int cs = 0; cs < CSECT; ++cs) {
        __syncthreads();
        for (int i = tid; i < SPIX * CB16; i += 256) {
            int pix = i / CB16, sub = i - pix * CB16;
            int prow = y0 + pix / Wst, pcol = pix % Wst;
            uint4 vh = {0, 0, 0, 0}, vl = {0, 0, 0, 0};
            if (prow < Hp) {
                size_t g = (((size_t)b * Hp + prow) * Wst + pcol) * (size_t)(C * 2)
                         + (size_t)cs * SECB + (size_t)sub * 16;
                vh = *(const uint4*)((const char*)Ahi + g);
                vl = *(const uint4*)((const char*)Alo + g);
            }
            *(uint4*)(sm + pix * PSTR + sub * 16) = vh;
            *(uint4*)(sm + STAGEB + pix * PSTR + sub * 16) = vl;
        }
        __syncthreads();

        for (int s = 0; s < KH * KW; ++s) {
            int ky = s / KW, kx = s % KW;
            #pragma unroll
            for (int kc = 0; kc < KCS; ++kc) {
                int chunk = s * KCC + cs * KCS + kc;
                short8 ah[MFW], al[MFW];
                #pragma unroll
                for (int mi = 0; mi < MFW; ++mi) {
                    int mp0 = (wv * MFW + mi) * 16;
                    int mpix = ((mp0 / W) + ky) * Wst + (mp0 % W) + kx;
                    int off = (mpix + r) * PSTR + q * 16 + kc * 64;
                    ah[mi] = *(const short8*)(sm + off);
                    al[mi] = *(const short8*)(sm + STAGEB + off);
                }
                #pragma unroll
                for (int ni = 0; ni < NF; ++ni) {
                    int nfg = blockIdx.y * NF + ni;
                    const u16* bt = Bp + ((size_t)(chunk * 2) * NFTOT + nfg) * 512 + l * 8;
                    short8 bh = *(const short8*)bt;
                    short8 bl = *(const short8*)(bt + (size_t)NFTOT * 512);
                    #pragma unroll
                    for (int mi = 0; mi < MFW; ++mi) {
                        acc[mi][ni] = __builtin_amdgcn_mfma_f32_16x16x32_bf16(ah[mi], bh, acc[mi][ni], 0, 0, 0);
                        acc[mi][ni] = __builtin_amdgcn_mfma_f32_16x16x32_bf16(ah[mi], bl, acc[mi][ni], 0, 0, 0);
                        acc[mi][ni] = __builtin_amdgcn_mfma_f32_16x16x32_bf16(al[mi], bh, acc[mi][ni], 0, 0, 0);
                    }
                }
            }
        }
    }

    if (OUTMODE == 2) {
        #pragma unroll
        for (int ni = 0; ni < NF; ++ni) {
            int nn = (blockIdx.y * NF + ni) * 16 + r;
            float bi0 = (nn < OC) ? ebi[nn] : 0.f;
            #pragma unroll
            for (int mi = 0; mi < MFW; ++mi) {
                #pragma unroll
                for (int j = 0; j < 4; ++j) {
                    int t = y0 + (wv * MFW + mi) * 16 + q * 4 + j;
                    if (t < H && nn < OC) {
                        float v = acc[mi][ni][j] + bi0;
                        Of[((size_t)b * H + t) * (size_t)OC + nn] = (v >= 0.f) ? v : 0.1f * v;
                    }
                }
            }
        }
    } else {
        __syncthreads();
        float* pt = (float*)sm;
        #pragma unroll
        for (int mi = 0; mi < MFW; ++mi)
            #pragma unroll
            for (int ni = 0; ni < NF; ++ni)
                #pragma unroll
                for (int j = 0; j < 4; ++j) {
                    int mp = (wv * MFW + mi) * 16 + q * 4 + j;
                    pt[mp * OCB + ni * 16 + r] = acc[mi][ni][j];
                }
        __syncthreads();
        constexpr int HO = H / 2, WO = W / 2;
        for (int i = tid; i < (R / 2) * WO * OCB; i += 256) {
            int c = i % OCB;
            int rem = i / OCB;
            int x2 = rem % WO;
            int y2 = rem / WO;
            int oc = blockIdx.y * OCB + c;
            float sc0 = 0.f, bi0 = 0.f;
            if (oc < OC) { sc0 = esc[oc]; bi0 = ebi[oc]; }
            float m = -3.4e38f;
            #pragma unroll
            for (int dy = 0; dy < 2; ++dy)
                #pragma unroll
                for (int dx = 0; dx < 2; ++dx) {
                    float v = fmaf(pt[((2 * y2 + dy) * W + 2 * x2 + dx) * OCB + c], sc0, bi0);
                    m = fmaxf(m, v);
                }
            m = fmaxf(m, 0.f);
            if (OUTMODE == 0) {
                size_t o = (((size_t)b * (HO + 2) + (y0 / 2 + y2 + 1)) * (WO + 2) + (x2 + 1)) * (size_t)OC + oc;
                u16 hh = f2bf(m);
                Ohi[o] = hh;
                Olo[o] = f2bf(m - bf2f(hh));
            } else {
                if (oc < OC)
                    Of[(((size_t)b * HO + (y0 / 2 + y2)) * WO + x2) * (size_t)OC + oc] = m;
            }
        }
    }
}

// ---------------------------------------------------------------------------
// FC: z (b, 64 pix, 257 f) NHWC f32 -> zfc (b, f, 32)
// ---------------------------------------------------------------------------
__global__ __launch_bounds__(256) void fc_kernel(
    const float* __restrict__ z, const float* __restrict__ fw,
    const float* __restrict__ fb, float* __restrict__ zfc)
{
    int bid = blockIdx.x;
    int ftile = bid % 33;
    int b = bid / 33;
    int j = threadIdx.x & 31;
    int f = ftile * 8 + (threadIdx.x >> 5);
    if (f >= 257) return;
    const float* zb = z + (size_t)b * 16448;
    float a = fb[j];
    #pragma unroll 8
    for (int s = 0; s < 64; ++s) a = fmaf(zb[s * 257 + f], fw[j * 64 + s], a);
    zfc[((size_t)b * 257 + f) * 32 + j] = a;
}

// ---------------------------------------------------------------------------
// Per-thread 4x4 Hermitian eigh (complex Jacobi, f64) -> Re(Un Un^H)
// ---------------------------------------------------------------------------
__global__ __launch_bounds__(64) void eigh_kernel(const float* __restrict__ z, double* __restrict__ rp)
{
    int idx = blockIdx.x * 64 + threadIdx.x;
    if (idx >= NB * NFB) return;
    const float* zr = z + (size_t)idx * 32;
    double Ar[4][4], Ai[4][4], Vr[4][4], Vi[4][4];
    #pragma unroll
    for (int m = 0; m < 4; ++m)
        #pragma unroll
        for (int n = 0; n < 4; ++n) {
            Ar[m][n] = 0.5 * ((double)zr[m * 8 + n] + (double)zr[n * 8 + m]);
            Ai[m][n] = 0.5 * ((double)zr[m * 8 + n + 4] - (double)zr[n * 8 + m + 4]);
            Vr[m][n] = (m == n) ? 1.0 : 0.0;
            Vi[m][n] = 0.0;
        }
    #pragma unroll
    for (int m = 0; m < 4; ++m) Ar[m][m] += 1e-5;

    for (int sweep = 0; sweep < 8; ++sweep) {
        #pragma unroll
        for (int p = 0; p < 3; ++p)
            #pragma unroll
            for (int qq = p + 1; qq < 4; ++qq) {
                double apr = Ar[p][qq], api = Ai[p][qq];
                double rmod = sqrt(apr * apr + api * api);
                if (rmod < 1e-300) continue;
                double cph = apr / rmod, sph = api / rmod;
                double tau = (Ar[qq][qq] - Ar[p][p]) / (2.0 * rmod);
                double t = (tau >= 0.0) ? (-1.0 / (tau + sqrt(1.0 + tau * tau)))
                                        : (1.0 / (-tau + sqrt(1.0 + tau * tau)));
                double c = 1.0 / sqrt(1.0 + t * t);
                double s = t * c;
                double wr = s * cph, wi = s * sph;
                #pragma unroll
                for (int i = 0; i < 4; ++i) {
                    double xr = Ar[i][p], xi = Ai[i][p];
                    double yr = Ar[i][qq], yi = Ai[i][qq];
                    Ar[i][p] = c * xr + (wr * yr + wi * yi);
                    Ai[i][p] = c * xi + (wr * yi - wi * yr);
                    Ar[i][qq] = c * yr - (wr * xr - wi * xi);
                    Ai[i][qq] = c * yi - (wr * xi + wi * xr);
                }
                #pragma unroll
                for (int i = 0; i < 4; ++i) {
                    double xr = Ar[p][i], xi = Ai[p][i];
                    double yr = Ar[qq][i], yi = Ai[qq][i];
                    Ar[p][i] = c * xr + (wr * yr - wi * yi);
                    Ai[p][i] = c * xi + (wr * yi + wi * yr);
                    Ar[qq][i] = c * yr - (wr * xr + wi * xi);
                    Ai[qq][i] = c * yi - (wr * xi - wi * xr);
                }
                #pragma unroll
                for (int i = 0; i < 4; ++i) {
                    double xr = Vr[i][p], xi = Vi[i][p];
                    double yr = Vr[i][qq], yi = Vi[i][qq];
                    Vr[i][p] = c * xr + (wr * yr + wi * yi);
                    Vi[i][p] = c * xi + (wr * yi - wi * yr);
                    Vr[i][qq] = c * yr - (wr * xr - wi * xi);
                    Vi[i][qq] = c * yi - (wr * xi + wi * xr);
                }
            }
    }
    double ev[4] = {Ar[0][0], Ar[1][1], Ar[2][2], Ar[3][3]};
    int i0 = 0;
    #pragma unroll
    for (int k = 1; k < 4; ++k) if (ev[k] < ev[i0]) i0 = k;
    int i1 = (i0 == 0) ? 1 : 0;
    #pragma unroll
    for (int k = 0; k < 4; ++k) if (k != i0 && ev[k] < ev[i1]) i1 = k;
    double* o = rp + (size_t)idx * 16;
    #pragma unroll
    for (int m = 0; m < 4; ++m)
        #pragma unroll
        for (int n = 0; n < 4; ++n)
            o[m * 4 + n] = Vr[m][i0] * Vr[n][i0] + Vi[m][i0] * Vi[n][i0]
                         + Vr[m][i1] * Vr[n][i1] + Vi[m][i1] * Vi[n][i1];
}

// ---------------------------------------------------------------------------
// MUSIC spectrum -> transposed padded split output (b, t=a+1 in 362, f in 288)
// ---------------------------------------------------------------------------
__global__ __launch_bounds__(256) void music_kernel(
    const float4* __restrict__ svr, const float4* __restrict__ svi,
    const double* __restrict__ rp, u16* __restrict__ muhi, u16* __restrict__ mulo)
{
    __shared__ double P[32][16];
    __shared__ float T[32][33];
    int bid = blockIdx.x;
    int at = bid % 12; bid /= 12;
    int ft = bid % 9;
    int b = bid / 9;
    int f0 = ft * 32, a0 = at * 32;
    int tid = threadIdx.x;
    for (int i = tid; i < 32 * 16; i += 256) {
        int fi = i >> 4, j = i & 15;
        int f = f0 + fi;
        P[fi][j] = (f < 257) ? rp[((size_t)b * 257 + f) * 16 + j] : 0.0;
    }
    __syncthreads();
    int asub = tid & 31, fsub = tid >> 5;
    int a = a0 + asub;
    #pragma unroll
    for (int k2 = 0; k2 < 4; ++k2) {
        int fl = fsub + 8 * k2;
        int f = f0 + fl;
        float val = 0.f;
        if (a < 360 && f < 257) {
            float4 u = svr[((size_t)b * 257 + f) * 360 + a];
            float4 w = svi[((size_t)b * 257 + f) * 360 + a];
            const double* Pf = P[fl];
            double ua[4] = {u.x, u.y, u.z, u.w};
            double wa[4] = {w.x, w.y, w.z, w.w};
            double qa = 0.0, qb = 0.0;
            #pragma unroll
            for (int m = 0; m < 4; ++m)
                #pragma unroll
                for (int n = 0; n < 4; ++n) {
                    double pmn = Pf[m * 4 + n];
                    qa += pmn * ua[m] * ua[n];
                    qb += pmn * wa[m] * wa[n];
                }
            double den = qa - qb;
            val = (float)(1.0 / fmax(den, 1e-6));
        }
        T[asub][fl] = val;
    }
    __syncthreads();
    #pragma unroll
    for (int p = 0; p < 4; ++p) {
        int row = p * 8 + (tid >> 5);
        int fc = tid & 31;
        int a2 = a0 + row;
        if (a2 < 360) {
            float v = T[row][fc];
            size_t o = (((size_t)b * 362) + a2 + 1) * 288 + f0 + fc;
            u16 hh = f2bf(v);
            muhi[o] = hh;
            mulo[o] = f2bf(v - bf2f(hh));
        }
    }
}

// ---------------------------------------------------------------------------
// attention partial t-sums then finish (mean -> MLP -> sigmoid)
// ---------------------------------------------------------------------------
__global__ __launch_bounds__(256) void attn_partial(const float* __restrict__ sp2, float* __restrict__ part)
{
    int bid = blockIdx.x;
    int ch = bid % 6;
    int b = bid / 6;
    int t0 = ch * 60;
    for (int f = threadIdx.x; f < 257; f += 256) {
        float s = 0.f;
        for (int t = 0; t < 60; ++t) s += sp2[((size_t)b * 360 + t0 + t) * 257 + f];
        part[((size_t)b * 6 + ch) * 257 + f] = s;
    }
}

__global__ __launch_bounds__(256) void attn_finish(
    const float* __restrict__ part, const float* __restrict__ w1,
    const float* __restrict__ w2, float* __restrict__ att)
{
    __shared__ float ys[257];
    __shared__ float hs[16];
    int b = blockIdx.x;
    int tid = threadIdx.x;
    for (int f = tid; f < 257; f += 256) {
        float s = 0.f;
        #pragma unroll
        for (int c = 0; c < 6; ++c) s += part[((size_t)b * 6 + c) * 257 + f];
        ys[f] = s * (1.0f / 360.0f);
    }
    __syncthreads();
    if (tid < 16) {
        float h = 0.f;
        for (int c = 0; c < 257; ++c) h = fmaf(ys[c], w1[(size_t)tid * 257 + c], h);
        hs[tid] = fmaxf(h, 0.f);
    }
    __syncthreads();
    for (int o = tid; o < 257; o += 256) {
        float a = 0.f;
        #pragma unroll
        for (int j = 0; j < 16; ++j) a = fmaf(hs[j], w2[(size_t)o * 16 + j], a);
        att[(size_t)b * 257 + o] = 1.0f / (1.0f + expf(-a));
    }
}

// ---------------------------------------------------------------------------
// conv1d 257->1 over att-weighted sp2(b,t,f), sigmoid -> outS (b,360)
// ---------------------------------------------------------------------------
__global__ __launch_bounds__(256) void convs1_kernel(
    const float* __restrict__ sp2, const float* __restrict__ att,
    const float* __restrict__ w, const float* __restrict__ bb,
    float* __restrict__ outS)
{
    int bid = blockIdx.x;
    int tt = bid % 90;
    int b = bid / 90;
    int wv = threadIdx.x >> 6, l = threadIdx.x & 63;
    int t = tt * 4 + wv;
    float s = 0.f;
    for (int f = l; f < 257; f += 64) {
        float av = att[(size_t)b * 257 + f];
        float w0 = w[f * 3] * av, w1 = w[f * 3 + 1] * av, w2 = w[f * 3 + 2] * av;
        const float* col = sp2 + (size_t)b * 360 * 257 + f;
        if (t > 0)   s = fmaf(w0, col[(size_t)(t - 1) * 257], s);
        s = fmaf(w1, col[(size_t)t * 257], s);
        if (t < 359) s = fmaf(w2, col[(size_t)(t + 1) * 257], s);
    }
    #pragma unroll
    for (int off = 32; off > 0; off >>= 1) s += __shfl_down(s, off, 64);
    if (l == 0) outS[(size_t)b * 360 + t] = 1.0f / (1.0f + expf(-(s + bb[0])));
}

// ---------------------------------------------------------------------------
// top-5 soft-argmax, wave-parallel (strict >, index asc tie-break)
// ---------------------------------------------------------------------------
__global__ __launch_bounds__(64) void doa_kernel(const float* __restrict__ spec, float* __restrict__ doa)
{
    int b = blockIdx.x;
    int l = threadIdx.x;
    const float* s = spec + (size_t)b * NANG;
    float v[6];
    #pragma unroll
    for (int j = 0; j < 6; ++j) {
        int idx = l + 64 * j;
        v[j] = (idx < NANG) ? s[idx] : -3.4e38f;
    }
    float wvv[5]; int wii[5];
    #pragma unroll
    for (int k = 0; k < 5; ++k) {
        float bv = v[0]; int bj = 0;
        #pragma unroll
        for (int j = 1; j < 6; ++j)
            if (v[j] > bv) { bv = v[j]; bj = j; }
        int bi = l + 64 * bj;
        #pragma unroll
        for (int off = 1; off < 64; off <<= 1) {
            float ov = __shfl_xor(bv, off, 64);
            int oi = __shfl_xor(bi, off, 64);
            if (ov > bv || (ov == bv && oi < bi)) { bv = ov; bi = oi; }
        }
        wvv[k] = bv; wii[k] = bi;
        if ((bi & 63) == l) {
            int j = bi >> 6;
            #pragma unroll
            for (int jj = 0; jj < 6; ++jj)
                if (jj == j) v[jj] = -3.4e38f;
        }
    }
    if (l == 0) {
        float m = wvv[0];
        float wsum = 0.f, asum = 0.f;
        #pragma unroll
        for (int k = 0; k < 5; ++k) {
            float e = expf(20.0f * (wvv[k] - m));
            wsum += e;
            asum += e * (float)wii[k];
        }
        doa[b] = asum / wsum;
    }
}

// ---------------------------------------------------------------------------
extern "C" void kernel_launch(void* const* d_in, const int* in_sizes, int n_in,
                              void* d_out, int out_size, void* d_ws, size_t ws_size,
                              hipStream_t stream)
{
    const float* X    = (const float*)d_in[0];
    const float* svr  = (const float*)d_in[1];
    const float* svi  = (const float*)d_in[2];
    const float* c1w  = (const float*)d_in[4];
    const float* c2w  = (const float*)d_in[5];
    const float* c3w  = (const float*)d_in[6];
    const float* c4w  = (const float*)d_in[7];
    const float* fcw  = (const float*)d_in[8];
    const float* fcb  = (const float*)d_in[9];
    const float* s2w  = (const float*)d_in[10];
    const float* s2b  = (const float*)d_in[11];
    const float* s1w  = (const float*)d_in[12];
    const float* s1b  = (const float*)d_in[13];
    const float* caw1 = (const float*)d_in[14];
    const float* caw2 = (const float*)d_in[15];
    const float* bn1g = (const float*)d_in[16]; const float* bn1b = (const float*)d_in[17];
    const float* bn1m = (const float*)d_in[18]; const float* bn1v = (const float*)d_in[19];
    const float* bn2g = (const float*)d_in[20]; const float* bn2b = (const float*)d_in[21];
    const float* bn2m = (const float*)d_in[22]; const float* bn2v = (const float*)d_in[23];
    const float* bn3g = (const float*)d_in[24]; const float* bn3b = (const float*)d_in[25];
    const float* bn3m = (const float*)d_in[26]; const float* bn3v = (const float*)d_in[27];
    const float* bn4g = (const float*)d_in[28]; const float* bn4b = (const float*)d_in[29];
    const float* bn4m = (const float*)d_in[30]; const float* bn4v = (const float*)d_in[31];

    char* wsb = (char*)d_ws;
    // region A (time-disjoint: xp -> c3 -> mu)
    u16* xp_hi = (u16*)(wsb + 0);
    u16* xp_lo = (u16*)(wsb + 17305600);
    u16* c3_hi = (u16*)(wsb + 0);
    u16* c3_lo = (u16*)(wsb + 9469952);
    u16* mu_hi = (u16*)(wsb + 0);
    u16* mu_lo = (u16*)(wsb + 13344768);
    // region B (c2 -> {z, zfc, rp, sp2, part, att})
    const size_t Bb = 34611200;
    u16*   c2_hi = (u16*)(wsb + Bb);
    u16*   c2_lo = (u16*)(wsb + Bb + 35684352);
    float*  zbuf = (float*)(wsb + Bb);
    float*  zfc  = (float*)(wsb + Bb + 4210688);
    double* rp   = (double*)(wsb + Bb + 6316032);
    float*  sp2  = (float*)(wsb + Bb + 8421376);
    float*  part = (float*)(wsb + Bb + 32106496);
    float*  att  = (float*)(wsb + Bb + 32501248);
    // region C (persistent small)
    const size_t Cb = Bb + 71368704;
    u16* c4_hi = (u16*)(wsb + Cb);
    u16* c4_lo = (u16*)(wsb + Cb + 2654208);
    u16* bp1 = (u16*)(wsb + Cb + 5308416);
    u16* bp2 = (u16*)(wsb + Cb + 5382144);
    u16* bp3 = (u16*)(wsb + Cb + 5529600);
    u16* bp4 = (u16*)(wsb + Cb + 5677056);
    u16* bp5 = (u16*)(wsb + Cb + 6414336);
    float* bns = (float*)(wsb + Cb + 7409664);

    float* outD = (float*)d_out;
    float* outS = (float*)d_out + 64;

    // --- prep ---
    bnprep<<<4, 256, 0, stream>>>(bn1g, bn1b, bn1m, bn1v, bn2g, bn2b, bn2m, bn2v,
                                  bn3g, bn3b, bn3m, bn3v, bn4g, bn4b, bn4m, bn4v, bns);
    bpack1<<<6, 256, 0, stream>>>(c1w, bp1);
    bpack<<<36, 256, 0, stream>>>(c2w, bp2, 64, 64, 9, 2, 4);
    bpack<<<36, 256, 0, stream>>>(c3w, bp3, 64, 64, 9, 2, 4);
    bpack<<<180, 256, 0, stream>>>(c4w, bp4, 64, 257, 9, 2, 20);
    bpack<<<243, 256, 0, stream>>>(s2w, bp5, 257, 257, 3, 9, 18);
    xpack_kernel<<<64 * 130, 256, 0, stream>>>(X, xp_hi, xp_lo);
    zpad<<<4161, 256, 0, stream>>>(c2_hi, c2_lo, 64, 66, 66, 64, 1);
    zpad<<<1088, 256, 0, stream>>>(c4_hi, c4_lo, 64, 18, 18, 64, 1);

    // --- conv1 (K packs kx: 3 chunks) ---
    conv_c1<<<64 * 64, 256, 0, stream>>>(xp_hi, xp_lo, bp1, bns, bns + 512, c2_hi, c2_lo);
    zpad<<<2112, 256, 0, stream>>>(c3_hi, c3_lo, 64, 34, 34, 64, 1);  // A region free now
    // --- conv2 ---
    conv_gemm<64, 64, 64, 64, 2, 3, 3, 4, 2, 80, 0, 4, 2>
        <<<dim3(64 * 32, 1), 256, 0, stream>>>(c2_hi, c2_lo, bp2, bns + 1024, bns + 1536, c3_hi, c3_lo, nullptr);
    // --- conv3 ---
    conv_gemm<64, 32, 32, 64, 4, 3, 3, 4, 2, 80, 0, 4, 2>
        <<<dim3(64 * 8, 1), 256, 0, stream>>>(c3_hi, c3_lo, bp3, bns + 2048, bns + 2560, c4_hi, c4_lo, nullptr);
    zpad<<<144, 256, 0, stream>>>(mu_hi, mu_lo, 64, 362, 1, 288, 0);  // A region free now
    // --- conv4 -> z f32 (b,8,8,257) ---
    conv_gemm<64, 16, 16, 257, 8, 3, 3, 4, 2, 80, 1, 20, 2>
        <<<dim3(64 * 2, 5), 256, 0, stream>>>(c4_hi, c4_lo, bp4, bns + 3072, bns + 3584, nullptr, nullptr, zbuf);

    fc_kernel<<<64 * 33, 256, 0, stream>>>(zbuf, fcw, fcb, zfc);
    eigh_kernel<<<NFB, 64, 0, stream>>>(zfc, rp);
    music_kernel<<<64 * 108, 256, 0, stream>>>((const float4*)svr, (const float4*)svi, rp, mu_hi, mu_lo);
    // --- convs2 (1D conv as shift-GEMM) -> sp2 (b,t,f) ---
    conv_gemm<288, 360, 1, 257, 64, 3, 1, 9, 1, 208, 2, 18, 3>
        <<<dim3(64 * 6, 2), 256, 0, stream>>>(mu_hi, mu_lo, bp5, nullptr, s2b, nullptr, nullptr, sp2);

    attn_partial<<<64 * 6, 256, 0, stream>>>(sp2, part);
    attn_finish<<<64, 256, 0, stream>>>(part, caw1, caw2, att);
    convs1_kernel<<<64 * 90, 256, 0, stream>>>(sp2, att, s1w, s1b, outS);
    doa_kernel<<<64, 64, 0, stream>>>(outS, outD);
}

// Round 4
// 457.047 us; speedup vs baseline: 1.3680x; 1.3680x over previous
//
#include <hip/hip_runtime.h>

typedef unsigned short u16;
typedef unsigned int u32;
typedef short short8 __attribute__((ext_vector_type(8)));
typedef float f32x4 __attribute__((ext_vector_type(4)));

#define NB 64
#define NFB 257
#define NANG 360

__device__ __forceinline__ u16 f2bf(float x) {
    u32 u = __float_as_uint(x);
    u = (u + 0x7fffu + ((u >> 16) & 1u)) >> 16;
    return (u16)u;
}
__device__ __forceinline__ float bf2f(u16 h) { return __uint_as_float(((u32)h) << 16); }

// ---------------------------------------------------------------------------
// BN fold: scale = g*rsqrt(v+eps), bias = b - m*scale.  4 layers, 1 launch.
// ---------------------------------------------------------------------------
__global__ __launch_bounds__(256) void bnprep(
    const float* g1, const float* b1, const float* m1, const float* v1,
    const float* g2, const float* b2, const float* m2, const float* v2,
    const float* g3, const float* b3, const float* m3, const float* v3,
    const float* g4, const float* b4, const float* m4, const float* v4,
    float* out)
{
    int L = blockIdx.x;
    const float* gs[4] = {g1, g2, g3, g4};
    const float* bs[4] = {b1, b2, b3, b4};
    const float* ms[4] = {m1, m2, m3, m4};
    const float* vs[4] = {v1, v2, v3, v4};
    int n = (L == 3) ? 257 : 64;
    float* sc = out + L * 1024;
    float* bi = sc + 512;
    for (int i = threadIdx.x; i < n; i += 256) {
        float s = gs[L][i] * rsqrtf(vs[L][i] + 1e-5f);
        sc[i] = s;
        bi[i] = bs[L][i] - ms[L][i] * s;
    }
}

// ---------------------------------------------------------------------------
// Weight pack (generic): Bp[(chunk*2+h)*NFTOT + nf][lane][8] bf16,
// chunk = s*KCC + kc.  lane l: k = kc*32 + (l>>4)*8 + e, n = nf*16 + (l&15).
// w layout: w[(n*CREAL + k)*NT + s].
// ---------------------------------------------------------------------------
__global__ __launch_bounds__(256) void bpack(
    const float* __restrict__ w, u16* __restrict__ Bp,
    int CREAL, int OCREAL, int NT, int KCC, int NFTOT)
{
    int i = blockIdx.x * 256 + threadIdx.x;
    int total = NT * KCC * 2 * NFTOT * 64;
    if (i >= total) return;
    int lane = i & 63;
    int t = i >> 6;
    int nf = t % NFTOT;
    int th = t / NFTOT;
    int h = th & 1;
    int chunk = th >> 1;
    int s = chunk / KCC, kc = chunk % KCC;
    int n = nf * 16 + (lane & 15);
    int k0 = kc * 32 + (lane >> 4) * 8;
    u16 o8[8];
    #pragma unroll
    for (int e = 0; e < 8; ++e) {
        int k = k0 + e;
        float v = 0.f;
        if (k < CREAL && n < OCREAL) v = w[((size_t)n * CREAL + k) * NT + s];
        u16 hh = f2bf(v);
        o8[e] = (h == 0) ? hh : f2bf(v - bf2f(hh));
    }
    u16* d = Bp + (size_t)i * 8;
    #pragma unroll
    for (int e = 0; e < 8; ++e) d[e] = o8[e];
}

// ---------------------------------------------------------------------------
// Weight pack for conv1 (C=8, K = 4 pixels x 8 ch; kx=q in 0..3, kx=3 zero).
// ---------------------------------------------------------------------------
__global__ __launch_bounds__(256) void bpack1(const float* __restrict__ w, u16* __restrict__ Bp)
{
    int i = blockIdx.x * 256 + threadIdx.x;
    if (i >= 3 * 2 * 4 * 64) return;
    int lane = i & 63;
    int t = i >> 6;
    int nf = t % 4;
    int th = t / 4;
    int h = th & 1;
    int ky = th >> 1;
    int n = nf * 16 + (lane & 15);
    int q = lane >> 4;
    u16 o8[8];
    #pragma unroll
    for (int e = 0; e < 8; ++e) {
        float v = (q < 3) ? w[((size_t)(n * 8 + e) * 3 + ky) * 3 + q] : 0.f;
        u16 hh = f2bf(v);
        o8[e] = (h == 0) ? hh : f2bf(v - bf2f(hh));
    }
    u16* d = Bp + (size_t)i * 8;
    #pragma unroll
    for (int e = 0; e < 8; ++e) d[e] = o8[e];
}

// ---------------------------------------------------------------------------
// X (64,8,128,128) f32 NCHW -> padded NHWC bf16 hi/lo (b,130,130,8).
// ---------------------------------------------------------------------------
__global__ __launch_bounds__(256) void xpack_kernel(
    const float* __restrict__ X, u16* __restrict__ hi, u16* __restrict__ lo)
{
    __shared__ float Xs[8][132];
    int bid = blockIdx.x;
    int prow = bid % 130;
    int b = bid / 130;
    bool inr = (prow >= 1 && prow <= 128);
    for (int i = threadIdx.x; i < 8 * 130; i += 256) {
        int c = i / 130, pcol = i % 130;
        float v = 0.f;
        if (inr && pcol >= 1 && pcol <= 128)
            v = X[(((size_t)b * 8 + c) * 128 + (prow - 1)) * 128 + (pcol - 1)];
        Xs[c][pcol] = v;
    }
    __syncthreads();
    for (int p = threadIdx.x; p < 130; p += 256) {
        short8 h8, l8;
        #pragma unroll
        for (int c = 0; c < 8; ++c) {
            float f = Xs[c][p];
            u16 hh = f2bf(f);
            h8[c] = (short)hh;
            l8[c] = (short)f2bf(f - bf2f(hh));
        }
        size_t o = (((size_t)b * 130 + prow) * 130 + p) * 8;
        *(short8*)(hi + o) = h8;
        *(short8*)(lo + o) = l8;
    }
}

// ---------------------------------------------------------------------------
// Zero the padding border of a padded-NHWC bf16 hi/lo pair.
// ---------------------------------------------------------------------------
__global__ __launch_bounds__(256) void zpad(
    u16* hi, u16* lo, int Bn, int Hp, int Wp, int Cb, int doCols)
{
    int perB = 2 * Wp + (doCols ? 2 * (Hp - 2) : 0);
    long total = (long)Bn * perB * Cb;
    for (long idx = blockIdx.x * 256L + threadIdx.x; idx < total; idx += (long)gridDim.x * 256) {
        int c = (int)(idx % Cb);
        long t = idx / Cb;
        int p = (int)(t % perB);
        int b = (int)(t / perB);
        int row, col;
        if (p < Wp) { row = 0; col = p; }
        else if (p < 2 * Wp) { row = Hp - 1; col = p - Wp; }
        else { int pp = p - 2 * Wp; row = 1 + (pp >> 1); col = (pp & 1) ? (Wp - 1) : 0; }
        size_t o = (((size_t)b * Hp + row) * Wp + col) * Cb + c;
        hi[o] = 0;
        lo[o] = 0;
    }
}

// ---------------------------------------------------------------------------
// conv1 dedicated: C=8, K packs 4 pixels x 8 ch (kx in K).  3 chunks only.
// ---------------------------------------------------------------------------
__global__ __launch_bounds__(256) void conv_c1(
    const u16* __restrict__ Ahi, const u16* __restrict__ Alo,
    const u16* __restrict__ Bp,
    const float* __restrict__ esc, const float* __restrict__ ebi,
    u16* __restrict__ Ohi, u16* __restrict__ Olo)
{
    constexpr int Wst = 130, Hp = 130;
    constexpr int SROWS = 5;
    constexpr int SPIX = SROWS * Wst;
    constexpr int PSTR = 48;
    constexpr int STAGEB = SPIX * PSTR;
    constexpr int POOLB = 2 * 128 * 64 * 4;
    __shared__ __align__(16) char sm[POOLB + 64];

    int bid = blockIdx.x;
    int ytile = bid % 64;
    int b = bid / 64;
    int y0 = ytile * 2;
    int tid = threadIdx.x;
    int wv = tid >> 6;
    int l = tid & 63;
    int r = l & 15, q = l >> 4;

    for (int pix = tid; pix < SPIX; pix += 256) {
        int prow = y0 + pix / Wst, pcol = pix % Wst;
        uint4 vh = {0, 0, 0, 0}, vl = {0, 0, 0, 0};
        if (prow < Hp) {
            size_t g = (((size_t)b * Hp + prow) * Wst + pcol) * 16;
            vh = *(const uint4*)((const char*)Ahi + g);
            vl = *(const uint4*)((const char*)Alo + g);
        }
        *(uint4*)(sm + pix * PSTR) = vh;
        *(uint4*)(sm + STAGEB + pix * PSTR) = vl;
    }
    __syncthreads();

    f32x4 acc[4][4];
    #pragma unroll
    for (int mi = 0; mi < 4; ++mi)
        #pragma unroll
        for (int ni = 0; ni < 4; ++ni)
            acc[mi][ni] = (f32x4){0.f, 0.f, 0.f, 0.f};

    #pragma unroll
    for (int ky = 0; ky < 3; ++ky) {
        short8 ah[4], al[4];
        #pragma unroll
        for (int mi = 0; mi < 4; ++mi) {
            int mp0 = (wv * 4 + mi) * 16;
            int mpix = ((mp0 >> 7) + ky) * Wst + (mp0 & 127);
            int off = (mpix + r + q) * PSTR;
            ah[mi] = *(const short8*)(sm + off);
            al[mi] = *(const short8*)(sm + STAGEB + off);
        }
        #pragma unroll
        for (int ni = 0; ni < 4; ++ni) {
            const u16* bt = Bp + ((size_t)(ky * 2) * 4 + ni) * 512 + l * 8;
            short8 bh = *(const short8*)bt;
            short8 bl = *(const short8*)(bt + 4 * 512);
            #pragma unroll
            for (int mi = 0; mi < 4; ++mi) {
                acc[mi][ni] = __builtin_amdgcn_mfma_f32_16x16x32_bf16(ah[mi], bh, acc[mi][ni], 0, 0, 0);
                acc[mi][ni] = __builtin_amdgcn_mfma_f32_16x16x32_bf16(ah[mi], bl, acc[mi][ni], 0, 0, 0);
                acc[mi][ni] = __builtin_amdgcn_mfma_f32_16x16x32_bf16(al[mi], bh, acc[mi][ni], 0, 0, 0);
            }
        }
    }

    __syncthreads();
    float* pt = (float*)sm;
    #pragma unroll
    for (int mi = 0; mi < 4; ++mi)
        #pragma unroll
        for (int ni = 0; ni < 4; ++ni)
            #pragma unroll
            for (int j = 0; j < 4; ++j) {
                int mp = (wv * 4 + mi) * 16 + q * 4 + j;
                pt[mp * 64 + ni * 16 + r] = acc[mi][ni][j];
            }
    __syncthreads();
    for (int i = tid; i < 64 * 64; i += 256) {
        int c = i % 64;
        int x2 = i / 64;
        float sc0 = esc[c], bi0 = ebi[c];
        float m = -3.4e38f;
        #pragma unroll
        for (int dy = 0; dy < 2; ++dy)
            #pragma unroll
            for (int dx = 0; dx < 2; ++dx) {
                float v = fmaf(pt[(dy * 128 + 2 * x2 + dx) * 64 + c], sc0, bi0);
                m = fmaxf(m, v);
            }
        m = fmaxf(m, 0.f);
        size_t o = (((size_t)b * 66 + (y0 / 2 + 1)) * 66 + (x2 + 1)) * 64 + c;
        u16 hh = f2bf(m);
        Ohi[o] = hh;
        Olo[o] = f2bf(m - bf2f(hh));
    }
}

// ---------------------------------------------------------------------------
// Shift-GEMM conv via MFMA bf16 split (3 products), channel-sectioned staging.
// ---------------------------------------------------------------------------
template<int C, int H, int W, int OC, int R, int KH, int KW, int NF, int MFW,
         int PSTR, int OUTMODE, int NFTOT, int CSECT>
__global__ __launch_bounds__(256) void conv_gemm(
    const u16* __restrict__ Ahi, const u16* __restrict__ Alo,
    const u16* __restrict__ Bp,
    const float* __restrict__ esc, const float* __restrict__ ebi,
    u16* __restrict__ Ohi, u16* __restrict__ Olo, float* __restrict__ Of)
{
    constexpr int KCC = (C + 31) / 32;
    constexpr int KCS = KCC / CSECT;
    constexpr int SECB = (C / CSECT) * 2;
    constexpr int CB16 = SECB / 16;
    constexpr int Wst = W + KW - 1;
    constexpr int Hp = H + KH - 1;
    constexpr int SROWS = R + KH - 1;
    constexpr int SPIX = SROWS * Wst;
    constexpr int OCB = NF * 16;
    constexpr int HT = (H + R - 1) / R;
    constexpr int STAGEB = SPIX * PSTR;
    constexpr int POOLB = (OUTMODE == 2) ? 0 : (R * W * OCB * 4);
    constexpr int SMEMB = (2 * STAGEB > POOLB) ? (2 * STAGEB) : POOLB;
    __shared__ __align__(16) char sm[SMEMB + 64];

    int bid = blockIdx.x;
    int ytile = bid % HT;
    int b = bid / HT;
    int tid = threadIdx.x;
    int wv = tid >> 6;
    int l = tid & 63;
    int r = l & 15, q = l >> 4;
    int y0 = ytile * R;

    f32x4 acc[MFW][NF];
    #pragma unroll
    for (int mi = 0; mi < MFW; ++mi)
        #pragma unroll
        for (int ni = 0; ni < NF; ++ni)
            acc[mi][ni] = (f32x4){0.f, 0.f, 0.f, 0.f};

    for (int cs = 0; cs < CSECT; ++cs) {
        __syncthreads();
        for (int i = tid; i < SPIX * CB16; i += 256) {
            int pix = i / CB16, sub = i - pix * CB16;
            int prow = y0 + pix / Wst, pcol = pix % Wst;
            uint4 vh = {0, 0, 0, 0}, vl = {0, 0, 0, 0};
            if (prow < Hp) {
                size_t g = (((size_t)b * Hp + prow) * Wst + pcol) * (size_t)(C * 2)
                         + (size_t)cs * SECB + (size_t)sub * 16;
                vh = *(const uint4*)((const char*)Ahi + g);
                vl = *(const uint4*)((const char*)Alo + g);
            }
            *(uint4*)(sm + pix * PSTR + sub * 16) = vh;
            *(uint4*)(sm + STAGEB + pix * PSTR + sub * 16) = vl;
        }
        __syncthreads();

        for (int s = 0; s < KH * KW; ++s) {
            int ky = s / KW, kx = s % KW;
            #pragma unroll
            for (int kc = 0; kc < KCS; ++kc) {
                int chunk = s * KCC + cs * KCS + kc;
                short8 ah[MFW], al[MFW];
                #pragma unroll
                for (int mi = 0; mi < MFW; ++mi) {
                    int mp0 = (wv * MFW + mi) * 16;
                    int mpix = ((mp0 / W) + ky) * Wst + (mp0 % W) + kx;
                    int off = (mpix + r) * PSTR + q * 16 + kc * 64;
                    ah[mi] = *(const short8*)(sm + off);
                    al[mi] = *(const short8*)(sm + STAGEB + off);
                }
                #pragma unroll
                for (int ni = 0; ni < NF; ++ni) {
                    int nfg = blockIdx.y * NF + ni;
                    const u16* bt = Bp + ((size_t)(chunk * 2) * NFTOT + nfg) * 512 + l * 8;
                    short8 bh = *(const short8*)bt;
                    short8 bl = *(const short8*)(bt + (size_t)NFTOT * 512);
                    #pragma unroll
                    for (int mi = 0; mi < MFW; ++mi) {
                        acc[mi][ni] = __builtin_amdgcn_mfma_f32_16x16x32_bf16(ah[mi], bh, acc[mi][ni], 0, 0, 0);
                        acc[mi][ni] = __builtin_amdgcn_mfma_f32_16x16x32_bf16(ah[mi], bl, acc[mi][ni], 0, 0, 0);
                        acc[mi][ni] = __builtin_amdgcn_mfma_f32_16x16x32_bf16(al[mi], bh, acc[mi][ni], 0, 0, 0);
                    }
                }
            }
        }
    }

    if (OUTMODE == 2) {
        #pragma unroll
        for (int ni = 0; ni < NF; ++ni) {
            int nn = (blockIdx.y * NF + ni) * 16 + r;
            float bi0 = (nn < OC) ? ebi[nn] : 0.f;
            #pragma unroll
            for (int mi = 0; mi < MFW; ++mi) {
                #pragma unroll
                for (int j = 0; j < 4; ++j) {
                    int t = y0 + (wv * MFW + mi) * 16 + q * 4 + j;
                    if (t < H && nn < OC) {
                        float v = acc[mi][ni][j] + bi0;
                        Of[((size_t)b * H + t) * (size_t)OC + nn] = (v >= 0.f) ? v : 0.1f * v;
                    }
                }
            }
        }
    } else {
        __syncthreads();
        float* pt = (float*)sm;
        #pragma unroll
        for (int mi = 0; mi < MFW; ++mi)
            #pragma unroll
            for (int ni = 0; ni < NF; ++ni)
                #pragma unroll
                for (int j = 0; j < 4; ++j) {
                    int mp = (wv * MFW + mi) * 16 + q * 4 + j;
                    pt[mp * OCB + ni * 16 + r] = acc[mi][ni][j];
                }
        __syncthreads();
        constexpr int HO = H / 2, WO = W / 2;
        for (int i = tid; i < (R / 2) * WO * OCB; i += 256) {
            int c = i % OCB;
            int rem = i / OCB;
            int x2 = rem % WO;
            int y2 = rem / WO;
            int oc = blockIdx.y * OCB + c;
            float sc0 = 0.f, bi0 = 0.f;
            if (oc < OC) { sc0 = esc[oc]; bi0 = ebi[oc]; }
            float m = -3.4e38f;
            #pragma unroll
            for (int dy = 0; dy < 2; ++dy)
                #pragma unroll
                for (int dx = 0; dx < 2; ++dx) {
                    float v = fmaf(pt[((2 * y2 + dy) * W + 2 * x2 + dx) * OCB + c], sc0, bi0);
                    m = fmaxf(m, v);
                }
            m = fmaxf(m, 0.f);
            if (OUTMODE == 0) {
                size_t o = (((size_t)b * (HO + 2) + (y0 / 2 + y2 + 1)) * (WO + 2) + (x2 + 1)) * (size_t)OC + oc;
                u16 hh = f2bf(m);
                Ohi[o] = hh;
                Olo[o] = f2bf(m - bf2f(hh));
            } else {
                if (oc < OC)
                    Of[(((size_t)b * HO + (y0 / 2 + y2)) * WO + x2) * (size_t)OC + oc] = m;
            }
        }
    }
}

// ---------------------------------------------------------------------------
// convs2 as full-M B-reuse GEMM.  A: mu (b,362,288) bf16 hi/lo; B: bp5.
// Block: (b, ntile of 3 nf).  8 waves x 3 m-frags (48 t each) cover t<384.
// LDS: one 32-ch section of ALL 386 pixel rows, hi+lo (2x30880 B).
// Out: sp2 (b,360,257) f32, +bias, leaky_relu(0.1).
// ---------------------------------------------------------------------------
__global__ __launch_bounds__(512) void convs2_gemm(
    const u16* __restrict__ Ahi, const u16* __restrict__ Alo,
    const u16* __restrict__ Bp, const float* __restrict__ bia,
    float* __restrict__ sp2)
{
    constexpr int SPIX = 386;       // t = -1 .. 384 (rows >=362 zeroed)
    constexpr int PSTR = 80;        // 64 B data + 16 pad
    constexpr int STAGEB = SPIX * PSTR;
    __shared__ __align__(16) char sm[2 * STAGEB];

    int b = blockIdx.x;
    int nt = blockIdx.y;            // 0..5, 3 nf each
    int tid = threadIdx.x;
    int wv = tid >> 6;              // 0..7
    int l = tid & 63;
    int r = l & 15, q = l >> 4;

    f32x4 acc[3][3];
    #pragma unroll
    for (int mi = 0; mi < 3; ++mi)
        #pragma unroll
        for (int ni = 0; ni < 3; ++ni)
            acc[mi][ni] = (f32x4){0.f, 0.f, 0.f, 0.f};

    for (int cs = 0; cs < 9; ++cs) {
        __syncthreads();
        // stage 32-ch section of all pixel rows (hi, lo)
        for (int i = tid; i < SPIX * 4; i += 512) {
            int pix = i >> 2, sub = i & 3;
            uint4 vh = {0, 0, 0, 0}, vl = {0, 0, 0, 0};
            if (pix < 362) {
                size_t g = ((size_t)b * 362 + pix) * 576 + (size_t)cs * 64 + (size_t)sub * 16;
                vh = *(const uint4*)((const char*)Ahi + g);
                vl = *(const uint4*)((const char*)Alo + g);
            }
            *(uint4*)(sm + pix * PSTR + sub * 16) = vh;
            *(uint4*)(sm + STAGEB + pix * PSTR + sub * 16) = vl;
        }
        __syncthreads();

        #pragma unroll
        for (int ky = 0; ky < 3; ++ky) {
            int chunk = ky * 9 + cs;
            short8 bh[3], bl[3];
            #pragma unroll
            for (int ni = 0; ni < 3; ++ni) {
                const u16* bt = Bp + ((size_t)(chunk * 2) * 18 + nt * 3 + ni) * 512 + l * 8;
                bh[ni] = *(const short8*)bt;
                bl[ni] = *(const short8*)(bt + 18 * 512);
            }
            #pragma unroll
            for (int mi = 0; mi < 3; ++mi) {
                int off = ((wv * 3 + mi) * 16 + r + ky) * PSTR + q * 16;
                short8 ah = *(const short8*)(sm + off);
                short8 al = *(const short8*)(sm + STAGEB + off);
                #pragma unroll
                for (int ni = 0; ni < 3; ++ni) {
                    acc[mi][ni] = __builtin_amdgcn_mfma_f32_16x16x32_bf16(ah, bh[ni], acc[mi][ni], 0, 0, 0);
                    acc[mi][ni] = __builtin_amdgcn_mfma_f32_16x16x32_bf16(ah, bl[ni], acc[mi][ni], 0, 0, 0);
                    acc[mi][ni] = __builtin_amdgcn_mfma_f32_16x16x32_bf16(al, bh[ni], acc[mi][ni], 0, 0, 0);
                }
            }
        }
    }

    // epilogue: C/D col = r (n), row = q*4+j (t)
    #pragma unroll
    for (int ni = 0; ni < 3; ++ni) {
        int n = (nt * 3 + ni) * 16 + r;
        if (n >= NFB) continue;
        float bi0 = bia[n];
        #pragma unroll
        for (int mi = 0; mi < 3; ++mi) {
            int t0 = (wv * 3 + mi) * 16 + q * 4;
            #pragma unroll
            for (int j = 0; j < 4; ++j) {
                int t = t0 + j;
                if (t < NANG) {
                    float v = acc[mi][ni][j] + bi0;
                    sp2[((size_t)b * NANG + t) * NFB + n] = (v >= 0.f) ? v : 0.1f * v;
                }
            }
        }
    }
}

// ---------------------------------------------------------------------------
// FC: z (b, 64 pix, 257 f) NHWC f32 -> zfc (b, f, 32)
// ---------------------------------------------------------------------------
__global__ __launch_bounds__(256) void fc_kernel(
    const float* __restrict__ z, const float* __restrict__ fw,
    const float* __restrict__ fb, float* __restrict__ zfc)
{
    int bid = blockIdx.x;
    int ftile = bid % 33;
    int b = bid / 33;
    int j = threadIdx.x & 31;
    int f = ftile * 8 + (threadIdx.x >> 5);
    if (f >= 257) return;
    const float* zb = z + (size_t)b * 16448;
    float a = fb[j];
    #pragma unroll 8
    for (int s = 0; s < 64; ++s) a = fmaf(zb[s * 257 + f], fw[j * 64 + s], a);
    zfc[((size_t)b * 257 + f) * 32 + j] = a;
}

// ---------------------------------------------------------------------------
// Per-thread 4x4 Hermitian eigh (complex Jacobi, f64) -> Re(Un Un^H)
// ---------------------------------------------------------------------------
__global__ __launch_bounds__(64) void eigh_kernel(const float* __restrict__ z, double* __restrict__ rp)
{
    int idx = blockIdx.x * 64 + threadIdx.x;
    if (idx >= NB * NFB) return;
    const float* zr = z + (size_t)idx * 32;
    double Ar[4][4], Ai[4][4], Vr[4][4], Vi[4][4];
    #pragma unroll
    for (int m = 0; m < 4; ++m)
        #pragma unroll
        for (int n = 0; n < 4; ++n) {
            Ar[m][n] = 0.5 * ((double)zr[m * 8 + n] + (double)zr[n * 8 + m]);
            Ai[m][n] = 0.5 * ((double)zr[m * 8 + n + 4] - (double)zr[n * 8 + m + 4]);
            Vr[m][n] = (m == n) ? 1.0 : 0.0;
            Vi[m][n] = 0.0;
        }
    #pragma unroll
    for (int m = 0; m < 4; ++m) Ar[m][m] += 1e-5;

    for (int sweep = 0; sweep < 8; ++sweep) {
        #pragma unroll
        for (int p = 0; p < 3; ++p)
            #pragma unroll
            for (int qq = p + 1; qq < 4; ++qq) {
                double apr = Ar[p][qq], api = Ai[p][qq];
                double rmod = sqrt(apr * apr + api * api);
                if (rmod < 1e-300) continue;
                double cph = apr / rmod, sph = api / rmod;
                double tau = (Ar[qq][qq] - Ar[p][p]) / (2.0 * rmod);
                double t = (tau >= 0.0) ? (-1.0 / (tau + sqrt(1.0 + tau * tau)))
                                        : (1.0 / (-tau + sqrt(1.0 + tau * tau)));
                double c = 1.0 / sqrt(1.0 + t * t);
                double s = t * c;
                double wr = s * cph, wi = s * sph;
                #pragma unroll
                for (int i = 0; i < 4; ++i) {
                    double xr = Ar[i][p], xi = Ai[i][p];
                    double yr = Ar[i][qq], yi = Ai[i][qq];
                    Ar[i][p] = c * xr + (wr * yr + wi * yi);
                    Ai[i][p] = c * xi + (wr * yi - wi * yr);
                    Ar[i][qq] = c * yr - (wr * xr - wi * xi);
                    Ai[i][qq] = c * yi - (wr * xi + wi * xr);
                }
                #pragma unroll
                for (int i = 0; i < 4; ++i) {
                    double xr = Ar[p][i], xi = Ai[p][i];
                    double yr = Ar[qq][i], yi = Ai[qq][i];
                    Ar[p][i] = c * xr + (wr * yr - wi * yi);
                    Ai[p][i] = c * xi + (wr * yi + wi * yr);
                    Ar[qq][i] = c * yr - (wr * xr + wi * xi);
                    Ai[qq][i] = c * yi - (wr * xi - wi * xr);
                }
                #pragma unroll
                for (int i = 0; i < 4; ++i) {
                    double xr = Vr[i][p], xi = Vi[i][p];
                    double yr = Vr[i][qq], yi = Vi[i][qq];
                    Vr[i][p] = c * xr + (wr * yr + wi * yi);
                    Vi[i][p] = c * xi + (wr * yi - wi * yr);
                    Vr[i][qq] = c * yr - (wr * xr - wi * xi);
                    Vi[i][qq] = c * yi - (wr * xi + wi * xr);
                }
            }
    }
    double ev[4] = {Ar[0][0], Ar[1][1], Ar[2][2], Ar[3][3]};
    int i0 = 0;
    #pragma unroll
    for (int k = 1; k < 4; ++k) if (ev[k] < ev[i0]) i0 = k;
    int i1 = (i0 == 0) ? 1 : 0;
    #pragma unroll
    for (int k = 0; k < 4; ++k) if (k != i0 && ev[k] < ev[i1]) i1 = k;
    double* o = rp + (size_t)idx * 16;
    #pragma unroll
    for (int m = 0; m < 4; ++m)
        #pragma unroll
        for (int n = 0; n < 4; ++n)
            o[m * 4 + n] = Vr[m][i0] * Vr[n][i0] + Vi[m][i0] * Vi[n][i0]
                         + Vr[m][i1] * Vr[n][i1] + Vi[m][i1] * Vi[n][i1];
}

// ---------------------------------------------------------------------------
// MUSIC spectrum -> transposed padded split output (b, t=a+1 in 362, f in 288)
// ---------------------------------------------------------------------------
__global__ __launch_bounds__(256) void music_kernel(
    const float4* __restrict__ svr, const float4* __restrict__ svi,
    const double* __restrict__ rp, u16* __restrict__ muhi, u16* __restrict__ mulo)
{
    __shared__ double P[32][16];
    __shared__ float T[32][33];
    int bid = blockIdx.x;
    int at = bid % 12; bid /= 12;
    int ft = bid % 9;
    int b = bid / 9;
    int f0 = ft * 32, a0 = at * 32;
    int tid = threadIdx.x;
    for (int i = tid; i < 32 * 16; i += 256) {
        int fi = i >> 4, j = i & 15;
        int f = f0 + fi;
        P[fi][j] = (f < 257) ? rp[((size_t)b * 257 + f) * 16 + j] : 0.0;
    }
    __syncthreads();
    int asub = tid & 31, fsub = tid >> 5;
    int a = a0 + asub;
    #pragma unroll
    for (int k2 = 0; k2 < 4; ++k2) {
        int fl = fsub + 8 * k2;
        int f = f0 + fl;
        float val = 0.f;
        if (a < 360 && f < 257) {
            float4 u = svr[((size_t)b * 257 + f) * 360 + a];
            float4 w = svi[((size_t)b * 257 + f) * 360 + a];
            const double* Pf = P[fl];
            double ua[4] = {u.x, u.y, u.z, u.w};
            double wa[4] = {w.x, w.y, w.z, w.w};
            double qa = 0.0, qb = 0.0;
            #pragma unroll
            for (int m = 0; m < 4; ++m)
                #pragma unroll
                for (int n = 0; n < 4; ++n) {
                    double pmn = Pf[m * 4 + n];
                    qa += pmn * ua[m] * ua[n];
                    qb += pmn * wa[m] * wa[n];
                }
            double den = qa - qb;
            val = (float)(1.0 / fmax(den, 1e-6));
        }
        T[asub][fl] = val;
    }
    __syncthreads();
    #pragma unroll
    for (int p = 0; p < 4; ++p) {
        int row = p * 8 + (tid >> 5);
        int fc = tid & 31;
        int a2 = a0 + row;
        if (a2 < 360) {
            float v = T[row][fc];
            size_t o = (((size_t)b * 362) + a2 + 1) * 288 + f0 + fc;
            u16 hh = f2bf(v);
            muhi[o] = hh;
            mulo[o] = f2bf(v - bf2f(hh));
        }
    }
}

// ---------------------------------------------------------------------------
// attention partial t-sums then finish (mean -> MLP -> sigmoid)
// ---------------------------------------------------------------------------
__global__ __launch_bounds__(256) void attn_partial(const float* __restrict__ sp2, float* __restrict__ part)
{
    int bid = blockIdx.x;
    int ch = bid % 6;
    int b = bid / 6;
    int t0 = ch * 60;
    for (int f = threadIdx.x; f < 257; f += 256) {
        float s = 0.f;
        for (int t = 0; t < 60; ++t) s += sp2[((size_t)b * 360 + t0 + t) * 257 + f];
        part[((size_t)b * 6 + ch) * 257 + f] = s;
    }
}

__global__ __launch_bounds__(256) void attn_finish(
    const float* __restrict__ part, const float* __restrict__ w1,
    const float* __restrict__ w2, float* __restrict__ att)
{
    __shared__ float ys[257];
    __shared__ float hs[16];
    int b = blockIdx.x;
    int tid = threadIdx.x;
    for (int f = tid; f < 257; f += 256) {
        float s = 0.f;
        #pragma unroll
        for (int c = 0; c < 6; ++c) s += part[((size_t)b * 6 + c) * 257 + f];
        ys[f] = s * (1.0f / 360.0f);
    }
    __syncthreads();
    if (tid < 16) {
        float h = 0.f;
        for (int c = 0; c < 257; ++c) h = fmaf(ys[c], w1[(size_t)tid * 257 + c], h);
        hs[tid] = fmaxf(h, 0.f);
    }
    __syncthreads();
    for (int o = tid; o < 257; o += 256) {
        float a = 0.f;
        #pragma unroll
        for (int j = 0; j < 16; ++j) a = fmaf(hs[j], w2[(size_t)o * 16 + j], a);
        att[(size_t)b * 257 + o] = 1.0f / (1.0f + expf(-a));
    }
}

// ---------------------------------------------------------------------------
// conv1d 257->1 over att-weighted sp2(b,t,f), sigmoid -> outS (b,360)
// ---------------------------------------------------------------------------
__global__ __launch_bounds__(256) void convs1_kernel(
    const float* __restrict__ sp2, const float* __restrict__ att,
    const float* __restrict__ w, const float* __restrict__ bb,
    float* __restrict__ outS)
{
    int bid = blockIdx.x;
    int tt = bid % 90;
    int b = bid / 90;
    int wv = threadIdx.x >> 6, l = threadIdx.x & 63;
    int t = tt * 4 + wv;
    float s = 0.f;
    for (int f = l; f < 257; f += 64) {
        float av = att[(size_t)b * 257 + f];
        float w0 = w[f * 3] * av, w1 = w[f * 3 + 1] * av, w2 = w[f * 3 + 2] * av;
        const float* col = sp2 + (size_t)b * 360 * 257 + f;
        if (t > 0)   s = fmaf(w0, col[(size_t)(t - 1) * 257], s);
        s = fmaf(w1, col[(size_t)t * 257], s);
        if (t < 359) s = fmaf(w2, col[(size_t)(t + 1) * 257], s);
    }
    #pragma unroll
    for (int off = 32; off > 0; off >>= 1) s += __shfl_down(s, off, 64);
    if (l == 0) outS[(size_t)b * 360 + t] = 1.0f / (1.0f + expf(-(s + bb[0])));
}

// ---------------------------------------------------------------------------
// top-5 soft-argmax, wave-parallel (strict >, index asc tie-break)
// ---------------------------------------------------------------------------
__global__ __launch_bounds__(64) void doa_kernel(const float* __restrict__ spec, float* __restrict__ doa)
{
    int b = blockIdx.x;
    int l = threadIdx.x;
    const float* s = spec + (size_t)b * NANG;
    float v[6];
    #pragma unroll
    for (int j = 0; j < 6; ++j) {
        int idx = l + 64 * j;
        v[j] = (idx < NANG) ? s[idx] : -3.4e38f;
    }
    float wvv[5]; int wii[5];
    #pragma unroll
    for (int k = 0; k < 5; ++k) {
        float bv = v[0]; int bj = 0;
        #pragma unroll
        for (int j = 1; j < 6; ++j)
            if (v[j] > bv) { bv = v[j]; bj = j; }
        int bi = l + 64 * bj;
        #pragma unroll
        for (int off = 1; off < 64; off <<= 1) {
            float ov = __shfl_xor(bv, off, 64);
            int oi = __shfl_xor(bi, off, 64);
            if (ov > bv || (ov == bv && oi < bi)) { bv = ov; bi = oi; }
        }
        wvv[k] = bv; wii[k] = bi;
        if ((bi & 63) == l) {
            int j = bi >> 6;
            #pragma unroll
            for (int jj = 0; jj < 6; ++jj)
                if (jj == j) v[jj] = -3.4e38f;
        }
    }
    if (l == 0) {
        float m = wvv[0];
        float wsum = 0.f, asum = 0.f;
        #pragma unroll
        for (int k = 0; k < 5; ++k) {
            float e = expf(20.0f * (wvv[k] - m));
            wsum += e;
            asum += e * (float)wii[k];
        }
        doa[b] = asum / wsum;
    }
}

// ---------------------------------------------------------------------------
extern "C" void kernel_launch(void* const* d_in, const int* in_sizes, int n_in,
                              void* d_out, int out_size, void* d_ws, size_t ws_size,
                              hipStream_t stream)
{
    const float* X    = (const float*)d_in[0];
    const float* svr  = (const float*)d_in[1];
    const float* svi  = (const float*)d_in[2];
    const float* c1w  = (const float*)d_in[4];
    const float* c2w  = (const float*)d_in[5];
    const float* c3w  = (const float*)d_in[6];
    const float* c4w  = (const float*)d_in[7];
    const float* fcw  = (const float*)d_in[8];
    const float* fcb  = (const float*)d_in[9];
    const float* s2w  = (const float*)d_in[10];
    const float* s2b  = (const float*)d_in[11];
    const float* s1w  = (const float*)d_in[12];
    const float* s1b  = (const float*)d_in[13];
    const float* caw1 = (const float*)d_in[14];
    const float* caw2 = (const float*)d_in[15];
    const float* bn1g = (const float*)d_in[16]; const float* bn1b = (const float*)d_in[17];
    const float* bn1m = (const float*)d_in[18]; const float* bn1v = (const float*)d_in[19];
    const float* bn2g = (const float*)d_in[20]; const float* bn2b = (const float*)d_in[21];
    const float* bn2m = (const float*)d_in[22]; const float* bn2v = (const float*)d_in[23];
    const float* bn3g = (const float*)d_in[24]; const float* bn3b = (const float*)d_in[25];
    const float* bn3m = (const float*)d_in[26]; const float* bn3v = (const float*)d_in[27];
    const float* bn4g = (const float*)d_in[28]; const float* bn4b = (const float*)d_in[29];
    const float* bn4m = (const float*)d_in[30]; const float* bn4v = (const float*)d_in[31];

    char* wsb = (char*)d_ws;
    // region A (time-disjoint: xp -> c3 -> mu)
    u16* xp_hi = (u16*)(wsb + 0);
    u16* xp_lo = (u16*)(wsb + 17305600);
    u16* c3_hi = (u16*)(wsb + 0);
    u16* c3_lo = (u16*)(wsb + 9469952);
    u16* mu_hi = (u16*)(wsb + 0);
    u16* mu_lo = (u16*)(wsb + 13344768);
    // region B (c2 -> {z, zfc, rp, sp2, part, att})
    const size_t Bb = 34611200;
    u16*   c2_hi = (u16*)(wsb + Bb);
    u16*   c2_lo = (u16*)(wsb + Bb + 35684352);
    float*  zbuf = (float*)(wsb + Bb);
    float*  zfc  = (float*)(wsb + Bb + 4210688);
    double* rp   = (double*)(wsb + Bb + 6316032);
    float*  sp2  = (float*)(wsb + Bb + 8421376);
    float*  part = (float*)(wsb + Bb + 32106496);
    float*  att  = (float*)(wsb + Bb + 32501248);
    // region C (persistent small)
    const size_t Cb = Bb + 71368704;
    u16* c4_hi = (u16*)(wsb + Cb);
    u16* c4_lo = (u16*)(wsb + Cb + 2654208);
    u16* bp1 = (u16*)(wsb + Cb + 5308416);
    u16* bp2 = (u16*)(wsb + Cb + 5382144);
    u16* bp3 = (u16*)(wsb + Cb + 5529600);
    u16* bp4 = (u16*)(wsb + Cb + 5677056);
    u16* bp5 = (u16*)(wsb + Cb + 6414336);
    float* bns = (float*)(wsb + Cb + 7409664);

    float* outD = (float*)d_out;
    float* outS = (float*)d_out + 64;

    // --- prep ---
    bnprep<<<4, 256, 0, stream>>>(bn1g, bn1b, bn1m, bn1v, bn2g, bn2b, bn2m, bn2v,
                                  bn3g, bn3b, bn3m, bn3v, bn4g, bn4b, bn4m, bn4v, bns);
    bpack1<<<6, 256, 0, stream>>>(c1w, bp1);
    bpack<<<36, 256, 0, stream>>>(c2w, bp2, 64, 64, 9, 2, 4);
    bpack<<<36, 256, 0, stream>>>(c3w, bp3, 64, 64, 9, 2, 4);
    bpack<<<180, 256, 0, stream>>>(c4w, bp4, 64, 257, 9, 2, 20);
    bpack<<<243, 256, 0, stream>>>(s2w, bp5, 257, 257, 3, 9, 18);
    xpack_kernel<<<64 * 130, 256, 0, stream>>>(X, xp_hi, xp_lo);
    zpad<<<4161, 256, 0, stream>>>(c2_hi, c2_lo, 64, 66, 66, 64, 1);
    zpad<<<1088, 256, 0, stream>>>(c4_hi, c4_lo, 64, 18, 18, 64, 1);

    // --- conv1 (K packs kx: 3 chunks) ---
    conv_c1<<<64 * 64, 256, 0, stream>>>(xp_hi, xp_lo, bp1, bns, bns + 512, c2_hi, c2_lo);
    zpad<<<2112, 256, 0, stream>>>(c3_hi, c3_lo, 64, 34, 34, 64, 1);  // A region free now
    // --- conv2 (round-2 config: CSECT=1, PSTR=144) ---
    conv_gemm<64, 64, 64, 64, 2, 3, 3, 4, 2, 144, 0, 4, 1>
        <<<dim3(64 * 32, 1), 256, 0, stream>>>(c2_hi, c2_lo, bp2, bns + 1024, bns + 1536, c3_hi, c3_lo, nullptr);
    // --- conv3 ---
    conv_gemm<64, 32, 32, 64, 4, 3, 3, 4, 2, 144, 0, 4, 1>
        <<<dim3(64 * 8, 1), 256, 0, stream>>>(c3_hi, c3_lo, bp3, bns + 2048, bns + 2560, c4_hi, c4_lo, nullptr);
    zpad<<<144, 256, 0, stream>>>(mu_hi, mu_lo, 64, 362, 1, 288, 0);  // A region free now
    // --- conv4 -> z f32 (b,8,8,257) ---
    conv_gemm<64, 16, 16, 257, 8, 3, 3, 4, 2, 144, 1, 20, 1>
        <<<dim3(64 * 2, 5), 256, 0, stream>>>(c4_hi, c4_lo, bp4, bns + 3072, bns + 3584, nullptr, nullptr, zbuf);

    fc_kernel<<<64 * 33, 256, 0, stream>>>(zbuf, fcw, fcb, zfc);
    eigh_kernel<<<NFB, 64, 0, stream>>>(zfc, rp);
    music_kernel<<<64 * 108, 256, 0, stream>>>((const float4*)svr, (const float4*)svi, rp, mu_hi, mu_lo);
    // --- convs2: full-M B-reuse GEMM -> sp2 (b,t,f) ---
    convs2_gemm<<<dim3(64, 6), 512, 0, stream>>>(mu_hi, mu_lo, bp5, s2b, sp2);

    attn_partial<<<64 * 6, 256, 0, stream>>>(sp2, part);
    attn_finish<<<64, 256, 0, stream>>>(part, caw1, caw2, att);
    convs1_kernel<<<64 * 90, 256, 0, stream>>>(sp2, att, s1w, s1b, outS);
    doa_kernel<<<64, 64, 0, stream>>>(outS, outD);
}

// Round 5
// 428.606 us; speedup vs baseline: 1.4587x; 1.0664x over previous
//
#include <hip/hip_runtime.h>

typedef unsigned short u16;
typedef unsigned int u32;
typedef short short8 __attribute__((ext_vector_type(8)));
typedef float f32x4 __attribute__((ext_vector_type(4)));

#define NB 64
#define NFB 257
#define NANG 360

__device__ __forceinline__ u16 f2bf(float x) {
    u32 u = __float_as_uint(x);
    u = (u + 0x7fffu + ((u >> 16) & 1u)) >> 16;
    return (u16)u;
}
__device__ __forceinline__ float bf2f(u16 h) { return __uint_as_float(((u32)h) << 16); }

// ---------------------------------------------------------------------------
// BN fold: scale = g*rsqrt(v+eps), bias = b - m*scale.  4 layers, 1 launch.
// ---------------------------------------------------------------------------
__global__ __launch_bounds__(256) void bnprep(
    const float* g1, const float* b1, const float* m1, const float* v1,
    const float* g2, const float* b2, const float* m2, const float* v2,
    const float* g3, const float* b3, const float* m3, const float* v3,
    const float* g4, const float* b4, const float* m4, const float* v4,
    float* out)
{
    int L = blockIdx.x;
    const float* gs[4] = {g1, g2, g3, g4};
    const float* bs[4] = {b1, b2, b3, b4};
    const float* ms[4] = {m1, m2, m3, m4};
    const float* vs[4] = {v1, v2, v3, v4};
    int n = (L == 3) ? 257 : 64;
    float* sc = out + L * 1024;
    float* bi = sc + 512;
    for (int i = threadIdx.x; i < n; i += 256) {
        float s = gs[L][i] * rsqrtf(vs[L][i] + 1e-5f);
        sc[i] = s;
        bi[i] = bs[L][i] - ms[L][i] * s;
    }
}

// ---------------------------------------------------------------------------
// Weight pack (generic): Bp[(chunk*2+h)*NFTOT + nf][lane][8] bf16,
// chunk = s*KCC + kc.  lane l: k = kc*32 + (l>>4)*8 + e, n = nf*16 + (l&15).
// ---------------------------------------------------------------------------
__global__ __launch_bounds__(256) void bpack(
    const float* __restrict__ w, u16* __restrict__ Bp,
    int CREAL, int OCREAL, int NT, int KCC, int NFTOT)
{
    int i = blockIdx.x * 256 + threadIdx.x;
    int total = NT * KCC * 2 * NFTOT * 64;
    if (i >= total) return;
    int lane = i & 63;
    int t = i >> 6;
    int nf = t % NFTOT;
    int th = t / NFTOT;
    int h = th & 1;
    int chunk = th >> 1;
    int s = chunk / KCC, kc = chunk % KCC;
    int n = nf * 16 + (lane & 15);
    int k0 = kc * 32 + (lane >> 4) * 8;
    u16 o8[8];
    #pragma unroll
    for (int e = 0; e < 8; ++e) {
        int k = k0 + e;
        float v = 0.f;
        if (k < CREAL && n < OCREAL) v = w[((size_t)n * CREAL + k) * NT + s];
        u16 hh = f2bf(v);
        o8[e] = (h == 0) ? hh : f2bf(v - bf2f(hh));
    }
    u16* d = Bp + (size_t)i * 8;
    #pragma unroll
    for (int e = 0; e < 8; ++e) d[e] = o8[e];
}

// ---------------------------------------------------------------------------
// Weight pack for conv1 (C=8, K = 4 pixels x 8 ch; kx=q in 0..3, kx=3 zero).
// ---------------------------------------------------------------------------
__global__ __launch_bounds__(256) void bpack1(const float* __restrict__ w, u16* __restrict__ Bp)
{
    int i = blockIdx.x * 256 + threadIdx.x;
    if (i >= 3 * 2 * 4 * 64) return;
    int lane = i & 63;
    int t = i >> 6;
    int nf = t % 4;
    int th = t / 4;
    int h = th & 1;
    int ky = th >> 1;
    int n = nf * 16 + (lane & 15);
    int q = lane >> 4;
    u16 o8[8];
    #pragma unroll
    for (int e = 0; e < 8; ++e) {
        float v = (q < 3) ? w[((size_t)(n * 8 + e) * 3 + ky) * 3 + q] : 0.f;
        u16 hh = f2bf(v);
        o8[e] = (h == 0) ? hh : f2bf(v - bf2f(hh));
    }
    u16* d = Bp + (size_t)i * 8;
    #pragma unroll
    for (int e = 0; e < 8; ++e) d[e] = o8[e];
}

// ---------------------------------------------------------------------------
// X (64,8,128,128) f32 NCHW -> padded NHWC bf16 hi/lo (b,130,130,8).
// ---------------------------------------------------------------------------
__global__ __launch_bounds__(256) void xpack_kernel(
    const float* __restrict__ X, u16* __restrict__ hi, u16* __restrict__ lo)
{
    __shared__ float Xs[8][132];
    int bid = blockIdx.x;
    int prow = bid % 130;
    int b = bid / 130;
    bool inr = (prow >= 1 && prow <= 128);
    for (int i = threadIdx.x; i < 8 * 130; i += 256) {
        int c = i / 130, pcol = i % 130;
        float v = 0.f;
        if (inr && pcol >= 1 && pcol <= 128)
            v = X[(((size_t)b * 8 + c) * 128 + (prow - 1)) * 128 + (pcol - 1)];
        Xs[c][pcol] = v;
    }
    __syncthreads();
    for (int p = threadIdx.x; p < 130; p += 256) {
        short8 h8, l8;
        #pragma unroll
        for (int c = 0; c < 8; ++c) {
            float f = Xs[c][p];
            u16 hh = f2bf(f);
            h8[c] = (short)hh;
            l8[c] = (short)f2bf(f - bf2f(hh));
        }
        size_t o = (((size_t)b * 130 + prow) * 130 + p) * 8;
        *(short8*)(hi + o) = h8;
        *(short8*)(lo + o) = l8;
    }
}

// ---------------------------------------------------------------------------
// Zero the padding border of a padded-NHWC bf16 hi/lo pair.
// ---------------------------------------------------------------------------
__global__ __launch_bounds__(256) void zpad(
    u16* hi, u16* lo, int Bn, int Hp, int Wp, int Cb, int doCols)
{
    int perB = 2 * Wp + (doCols ? 2 * (Hp - 2) : 0);
    long total = (long)Bn * perB * Cb;
    for (long idx = blockIdx.x * 256L + threadIdx.x; idx < total; idx += (long)gridDim.x * 256) {
        int c = (int)(idx % Cb);
        long t = idx / Cb;
        int p = (int)(t % perB);
        int b = (int)(t / perB);
        int row, col;
        if (p < Wp) { row = 0; col = p; }
        else if (p < 2 * Wp) { row = Hp - 1; col = p - Wp; }
        else { int pp = p - 2 * Wp; row = 1 + (pp >> 1); col = (pp & 1) ? (Wp - 1) : 0; }
        size_t o = (((size_t)b * Hp + row) * Wp + col) * Cb + c;
        hi[o] = 0;
        lo[o] = 0;
    }
}

// ---------------------------------------------------------------------------
// conv1 dedicated: C=8, K packs 4 pixels x 8 ch (kx in K).  3 chunks.
// In-register 2x2 pooling, tight 16B/pixel staging (20.8 KB LDS).
// ---------------------------------------------------------------------------
__global__ __launch_bounds__(256) void conv_c1(
    const u16* __restrict__ Ahi, const u16* __restrict__ Alo,
    const u16* __restrict__ Bp,
    const float* __restrict__ esc, const float* __restrict__ ebi,
    u16* __restrict__ Ohi, u16* __restrict__ Olo)
{
    constexpr int Wst = 130, Hp = 130;
    constexpr int SROWS = 5;                 // 2 rows + 2 halo + 1 wrap-guard
    constexpr int SPIX = SROWS * Wst;        // 650
    constexpr int STAGEB = SPIX * 16;        // 10400
    __shared__ __align__(16) char sm[2 * STAGEB];

    int bid = blockIdx.x;
    int ytile = bid % 64;
    int b = bid / 64;
    int y0 = ytile * 2;
    int tid = threadIdx.x;
    int wv = tid >> 6;
    int l = tid & 63;
    int r = l & 15, q = l >> 4;

    for (int pix = tid; pix < SPIX; pix += 256) {
        int prow = y0 + pix / Wst, pcol = pix % Wst;
        uint4 vh = {0, 0, 0, 0}, vl = {0, 0, 0, 0};
        if (prow < Hp) {
            size_t g = (((size_t)b * Hp + prow) * Wst + pcol) * 16;
            vh = *(const uint4*)((const char*)Ahi + g);
            vl = *(const uint4*)((const char*)Alo + g);
        }
        *(uint4*)(sm + pix * 16) = vh;
        *(uint4*)(sm + STAGEB + pix * 16) = vl;
    }
    __syncthreads();

    f32x4 acc[4][4] = {};

    #pragma unroll
    for (int ky = 0; ky < 3; ++ky) {
        short8 bh[4], bl[4];
        #pragma unroll
        for (int ni = 0; ni < 4; ++ni) {
            const u16* bt = Bp + ((size_t)(ky * 2) * 4 + ni) * 512 + l * 8;
            bh[ni] = *(const short8*)bt;
            bl[ni] = *(const short8*)(bt + 4 * 512);
        }
        short8 ah[4], al[4];
        #pragma unroll
        for (int mi = 0; mi < 4; ++mi) {
            int pf = wv * 2 + (mi >> 1);          // xf 0..7
            int y = mi & 1;
            int p = (y + ky) * Wst + pf * 16 + r + q;   // r+q wrap lands on guard row, zero-weighted
            ah[mi] = *(const short8*)(sm + p * 16);
            al[mi] = *(const short8*)(sm + STAGEB + p * 16);
        }
        #pragma unroll
        for (int ni = 0; ni < 4; ++ni)
            #pragma unroll
            for (int mi = 0; mi < 4; ++mi) {
                acc[mi][ni] = __builtin_amdgcn_mfma_f32_16x16x32_bf16(ah[mi], bh[ni], acc[mi][ni], 0, 0, 0);
                acc[mi][ni] = __builtin_amdgcn_mfma_f32_16x16x32_bf16(ah[mi], bl[ni], acc[mi][ni], 0, 0, 0);
                acc[mi][ni] = __builtin_amdgcn_mfma_f32_16x16x32_bf16(al[mi], bh[ni], acc[mi][ni], 0, 0, 0);
            }
    }

    // in-register BN+ReLU+2x2 pool.  acc[2pi+dmi][ni][2k+dj]: y=dmi, x=pf*16+q*4+2k+dj
    #pragma unroll
    for (int ni = 0; ni < 4; ++ni) {
        int oc = ni * 16 + r;
        float sc0 = esc[oc], bi0 = ebi[oc];
        #pragma unroll
        for (int pi = 0; pi < 2; ++pi) {
            int pf = wv * 2 + pi;
            #pragma unroll
            for (int k = 0; k < 2; ++k) {
                float m = -3.4e38f;
                #pragma unroll
                for (int dmi = 0; dmi < 2; ++dmi)
                    #pragma unroll
                    for (int dj = 0; dj < 2; ++dj)
                        m = fmaxf(m, fmaf(acc[2 * pi + dmi][ni][2 * k + dj], sc0, bi0));
                m = fmaxf(m, 0.f);
                int x2 = pf * 8 + q * 2 + k;
                size_t o = (((size_t)b * 66 + (y0 / 2 + 1)) * 66 + (x2 + 1)) * 64 + oc;
                u16 hh = f2bf(m);
                Ohi[o] = hh;
                Olo[o] = f2bf(m - bf2f(hh));
            }
        }
    }
}

// ---------------------------------------------------------------------------
// Shift-GEMM conv (C=64) via MFMA bf16 3-term split.  CSECT=2 (32-ch phases),
// XOR-swizzled exact-64B staging, depth-1 B prefetch, in-register pooling.
// OUTMODE 0: BN+ReLU+pool2 -> padded NHWC bf16 hi/lo
// OUTMODE 1: BN+ReLU+pool2 -> f32 NHWC
// ---------------------------------------------------------------------------
template<int H, int W, int OC, int R, int NF, int MFW, int OUTMODE, int NFTOT>
__global__ __launch_bounds__(256) void conv_gemm(
    const u16* __restrict__ Ahi, const u16* __restrict__ Alo,
    const u16* __restrict__ Bp,
    const float* __restrict__ esc, const float* __restrict__ ebi,
    u16* __restrict__ Ohi, u16* __restrict__ Olo, float* __restrict__ Of)
{
    constexpr int Wst = W + 2, Hp = H + 2;
    constexpr int SROWS = R + 2;
    constexpr int SPIX = SROWS * Wst;
    constexpr int XF = W / 16;
    constexpr int STAGEB = SPIX * 64;
    constexpr int HT = H / R;
    __shared__ __align__(16) char sm[2 * STAGEB];

    int bid = blockIdx.x;
    int ytile = bid % HT;
    int b = bid / HT;
    int tid = threadIdx.x;
    int wv = tid >> 6;
    int l = tid & 63;
    int r = l & 15, q = l >> 4;
    int y0 = ytile * R;
    int nfg0 = blockIdx.y * NF;

    f32x4 acc[MFW][NF] = {};
    short8 Bh[2][NF], Bl[2][NF];

    auto loadB = [&](int buf, int chunk) {
        #pragma unroll
        for (int ni = 0; ni < NF; ++ni) {
            const u16* bt = Bp + ((size_t)(chunk * 2) * NFTOT + nfg0 + ni) * 512 + l * 8;
            Bh[buf][ni] = *(const short8*)bt;
            Bl[buf][ni] = *(const short8*)(bt + (size_t)NFTOT * 512);
        }
    };
    loadB(0, 0);   // chunk = s*2+cs

    #pragma unroll
    for (int cs = 0; cs < 2; ++cs) {
        __syncthreads();
        for (int i = tid; i < SPIX * 4; i += 256) {
            int pix = i >> 2, sub = i & 3;
            int prow = y0 + pix / Wst, pcol = pix % Wst;
            uint4 vh = {0, 0, 0, 0}, vl = {0, 0, 0, 0};
            if (prow < Hp) {
                size_t g = (((size_t)b * Hp + prow) * Wst + pcol) * 128 + cs * 64 + sub * 16;
                vh = *(const uint4*)((const char*)Ahi + g);
                vl = *(const uint4*)((const char*)Alo + g);
            }
            int dst = (pix << 6) + ((sub ^ ((pix >> 1) & 3)) << 4);
            *(uint4*)(sm + dst) = vh;
            *(uint4*)(sm + STAGEB + dst) = vl;
        }
        __syncthreads();

        #pragma unroll
        for (int s = 0; s < 9; ++s) {
            int cur = (cs * 9 + s) & 1;
            if (s < 8) loadB(cur ^ 1, (s + 1) * 2 + cs);
            else if (cs == 0) loadB(cur ^ 1, 1);         // s=0 of section 1
            int ky = s / 3, kx = s % 3;
            short8 ah[MFW], al[MFW];
            #pragma unroll
            for (int mi = 0; mi < MFW; ++mi) {
                int pf = wv * (MFW / 2) + (mi >> 1);
                int y = (pf / XF) * 2 + (mi & 1);
                int xf = pf % XF;
                int p = (y + ky) * Wst + xf * 16 + kx + r;
                int off = (p << 6) + ((q ^ ((p >> 1) & 3)) << 4);
                ah[mi] = *(const short8*)(sm + off);
                al[mi] = *(const short8*)(sm + STAGEB + off);
            }
            #pragma unroll
            for (int ni = 0; ni < NF; ++ni)
                #pragma unroll
                for (int mi = 0; mi < MFW; ++mi) {
                    acc[mi][ni] = __builtin_amdgcn_mfma_f32_16x16x32_bf16(ah[mi], Bh[cur][ni], acc[mi][ni], 0, 0, 0);
                    acc[mi][ni] = __builtin_amdgcn_mfma_f32_16x16x32_bf16(ah[mi], Bl[cur][ni], acc[mi][ni], 0, 0, 0);
                    acc[mi][ni] = __builtin_amdgcn_mfma_f32_16x16x32_bf16(al[mi], Bh[cur][ni], acc[mi][ni], 0, 0, 0);
                }
        }
    }

    // in-register BN+ReLU+2x2 pool epilogue
    #pragma unroll
    for (int ni = 0; ni < NF; ++ni) {
        int oc = (nfg0 + ni) * 16 + r;
        float sc0 = esc[oc], bi0 = ebi[oc];   // bns regions are 512-padded: safe for oc<320
        #pragma unroll
        for (int pi = 0; pi < MFW / 2; ++pi) {
            int pf = wv * (MFW / 2) + pi;
            int y2 = y0 / 2 + pf / XF;
            int xb = (pf % XF) * 8 + q * 2;
            #pragma unroll
            for (int k = 0; k < 2; ++k) {
                float m = -3.4e38f;
                #pragma unroll
                for (int dmi = 0; dmi < 2; ++dmi)
                    #pragma unroll
                    for (int dj = 0; dj < 2; ++dj)
                        m = fmaxf(m, fmaf(acc[2 * pi + dmi][ni][2 * k + dj], sc0, bi0));
                m = fmaxf(m, 0.f);
                int x2 = xb + k;
                if (OUTMODE == 0) {
                    size_t o = (((size_t)b * (H / 2 + 2) + y2 + 1) * (W / 2 + 2) + (x2 + 1)) * 64 + oc;
                    u16 hh = f2bf(m);
                    Ohi[o] = hh;
                    Olo[o] = f2bf(m - bf2f(hh));
                } else {
                    if (oc < OC)
                        Of[(((size_t)b * (H / 2) + y2) * (W / 2) + x2) * (size_t)OC + oc] = m;
                }
            }
        }
    }
}

// ---------------------------------------------------------------------------
// convs2 as full-M B-reuse GEMM with swizzled staging + B prefetch.
// A: mu (b,362,288) bf16 hi/lo; out sp2 (b,360,257) f32 + bias + leaky.
// ---------------------------------------------------------------------------
__global__ __launch_bounds__(512) void convs2_gemm(
    const u16* __restrict__ Ahi, const u16* __restrict__ Alo,
    const u16* __restrict__ Bp, const float* __restrict__ bia,
    float* __restrict__ sp2)
{
    constexpr int SPIX = 386;
    constexpr int STAGEB = SPIX * 64;        // 24704
    __shared__ __align__(16) char sm[2 * STAGEB];

    int b = blockIdx.x;
    int nt = blockIdx.y;
    int tid = threadIdx.x;
    int wv = tid >> 6;
    int l = tid & 63;
    int r = l & 15, q = l >> 4;

    f32x4 acc[3][3] = {};
    short8 Bh[2][3], Bl[2][3];

    auto loadB = [&](int buf, int chunk) {
        #pragma unroll
        for (int ni = 0; ni < 3; ++ni) {
            const u16* bt = Bp + ((size_t)(chunk * 2) * 18 + nt * 3 + ni) * 512 + l * 8;
            Bh[buf][ni] = *(const short8*)bt;
            Bl[buf][ni] = *(const short8*)(bt + 18 * 512);
        }
    };
    loadB(0, 0);   // chunk = ky*9 + cs

    #pragma unroll
    for (int cs = 0; cs < 9; ++cs) {
        __syncthreads();
        for (int i = tid; i < SPIX * 4; i += 512) {
            int pix = i >> 2, sub = i & 3;
            uint4 vh = {0, 0, 0, 0}, vl = {0, 0, 0, 0};
            if (pix < 362) {
                size_t g = ((size_t)b * 362 + pix) * 576 + (size_t)cs * 64 + (size_t)sub * 16;
                vh = *(const uint4*)((const char*)Ahi + g);
                vl = *(const uint4*)((const char*)Alo + g);
            }
            int dst = (pix << 6) + ((sub ^ ((pix >> 1) & 3)) << 4);
            *(uint4*)(sm + dst) = vh;
            *(uint4*)(sm + STAGEB + dst) = vl;
        }
        __syncthreads();

        #pragma unroll
        for (int ky = 0; ky < 3; ++ky) {
            int cur = (cs * 3 + ky) & 1;
            if (ky < 2) loadB(cur ^ 1, (ky + 1) * 9 + cs);
            else if (cs < 8) loadB(cur ^ 1, cs + 1);
            #pragma unroll
            for (int mi = 0; mi < 3; ++mi) {
                int p = (wv * 3 + mi) * 16 + r + ky;
                int off = (p << 6) + ((q ^ ((p >> 1) & 3)) << 4);
                short8 ah = *(const short8*)(sm + off);
                short8 al = *(const short8*)(sm + STAGEB + off);
                #pragma unroll
                for (int ni = 0; ni < 3; ++ni) {
                    acc[mi][ni] = __builtin_amdgcn_mfma_f32_16x16x32_bf16(ah, Bh[cur][ni], acc[mi][ni], 0, 0, 0);
                    acc[mi][ni] = __builtin_amdgcn_mfma_f32_16x16x32_bf16(ah, Bl[cur][ni], acc[mi][ni], 0, 0, 0);
                    acc[mi][ni] = __builtin_amdgcn_mfma_f32_16x16x32_bf16(al, Bh[cur][ni], acc[mi][ni], 0, 0, 0);
                }
            }
        }
    }

    #pragma unroll
    for (int ni = 0; ni < 3; ++ni) {
        int n = (nt * 3 + ni) * 16 + r;
        if (n >= NFB) continue;
        float bi0 = bia[n];
        #pragma unroll
        for (int mi = 0; mi < 3; ++mi) {
            int t0 = (wv * 3 + mi) * 16 + q * 4;
            #pragma unroll
            for (int j = 0; j < 4; ++j) {
                int t = t0 + j;
                if (t < NANG) {
                    float v = acc[mi][ni][j] + bi0;
                    sp2[((size_t)b * NANG + t) * NFB + n] = (v >= 0.f) ? v : 0.1f * v;
                }
            }
        }
    }
}

// ---------------------------------------------------------------------------
// FC: z (b, 64 pix, 257 f) NHWC f32 -> zfc (b, f, 32)
// ---------------------------------------------------------------------------
__global__ __launch_bounds__(256) void fc_kernel(
    const float* __restrict__ z, const float* __restrict__ fw,
    const float* __restrict__ fb, float* __restrict__ zfc)
{
    int bid = blockIdx.x;
    int ftile = bid % 33;
    int b = bid / 33;
    int j = threadIdx.x & 31;
    int f = ftile * 8 + (threadIdx.x >> 5);
    if (f >= 257) return;
    const float* zb = z + (size_t)b * 16448;
    float a = fb[j];
    #pragma unroll 8
    for (int s = 0; s < 64; ++s) a = fmaf(zb[s * 257 + f], fw[j * 64 + s], a);
    zfc[((size_t)b * 257 + f) * 32 + j] = a;
}

// ---------------------------------------------------------------------------
// Per-thread 4x4 Hermitian eigh (complex Jacobi, f64) -> Re(Un Un^H)
// ---------------------------------------------------------------------------
__global__ __launch_bounds__(64) void eigh_kernel(const float* __restrict__ z, double* __restrict__ rp)
{
    int idx = blockIdx.x * 64 + threadIdx.x;
    if (idx >= NB * NFB) return;
    const float* zr = z + (size_t)idx * 32;
    double Ar[4][4], Ai[4][4], Vr[4][4], Vi[4][4];
    #pragma unroll
    for (int m = 0; m < 4; ++m)
        #pragma unroll
        for (int n = 0; n < 4; ++n) {
            Ar[m][n] = 0.5 * ((double)zr[m * 8 + n] + (double)zr[n * 8 + m]);
            Ai[m][n] = 0.5 * ((double)zr[m * 8 + n + 4] - (double)zr[n * 8 + m + 4]);
            Vr[m][n] = (m == n) ? 1.0 : 0.0;
            Vi[m][n] = 0.0;
        }
    #pragma unroll
    for (int m = 0; m < 4; ++m) Ar[m][m] += 1e-5;

    for (int sweep = 0; sweep < 8; ++sweep) {
        #pragma unroll
        for (int p = 0; p < 3; ++p)
            #pragma unroll
            for (int qq = p + 1; qq < 4; ++qq) {
                double apr = Ar[p][qq], api = Ai[p][qq];
                double rmod = sqrt(apr * apr + api * api);
                if (rmod < 1e-300) continue;
                double cph = apr / rmod, sph = api / rmod;
                double tau = (Ar[qq][qq] - Ar[p][p]) / (2.0 * rmod);
                double t = (tau >= 0.0) ? (-1.0 / (tau + sqrt(1.0 + tau * tau)))
                                        : (1.0 / (-tau + sqrt(1.0 + tau * tau)));
                double c = 1.0 / sqrt(1.0 + t * t);
                double s = t * c;
                double wr = s * cph, wi = s * sph;
                #pragma unroll
                for (int i = 0; i < 4; ++i) {
                    double xr = Ar[i][p], xi = Ai[i][p];
                    double yr = Ar[i][qq], yi = Ai[i][qq];
                    Ar[i][p] = c * xr + (wr * yr + wi * yi);
                    Ai[i][p] = c * xi + (wr * yi - wi * yr);
                    Ar[i][qq] = c * yr - (wr * xr - wi * xi);
                    Ai[i][qq] = c * yi - (wr * xi + wi * xr);
                }
                #pragma unroll
                for (int i = 0; i < 4; ++i) {
                    double xr = Ar[p][i], xi = Ai[p][i];
                    double yr = Ar[qq][i], yi = Ai[qq][i];
                    Ar[p][i] = c * xr + (wr * yr - wi * yi);
                    Ai[p][i] = c * xi + (wr * yi + wi * yr);
                    Ar[qq][i] = c * yr - (wr * xr + wi * xi);
                    Ai[qq][i] = c * yi - (wr * xi - wi * xr);
                }
                #pragma unroll
                for (int i = 0; i < 4; ++i) {
                    double xr = Vr[i][p], xi = Vi[i][p];
                    double yr = Vr[i][qq], yi = Vi[i][qq];
                    Vr[i][p] = c * xr + (wr * yr + wi * yi);
                    Vi[i][p] = c * xi + (wr * yi - wi * yr);
                    Vr[i][qq] = c * yr - (wr * xr - wi * xi);
                    Vi[i][qq] = c * yi - (wr * xi + wi * xr);
                }
            }
    }
    double ev[4] = {Ar[0][0], Ar[1][1], Ar[2][2], Ar[3][3]};
    int i0 = 0;
    #pragma unroll
    for (int k = 1; k < 4; ++k) if (ev[k] < ev[i0]) i0 = k;
    int i1 = (i0 == 0) ? 1 : 0;
    #pragma unroll
    for (int k = 0; k < 4; ++k) if (k != i0 && ev[k] < ev[i1]) i1 = k;
    double* o = rp + (size_t)idx * 16;
    #pragma unroll
    for (int m = 0; m < 4; ++m)
        #pragma unroll
        for (int n = 0; n < 4; ++n)
            o[m * 4 + n] = Vr[m][i0] * Vr[n][i0] + Vi[m][i0] * Vi[n][i0]
                         + Vr[m][i1] * Vr[n][i1] + Vi[m][i1] * Vi[n][i1];
}

// ---------------------------------------------------------------------------
// MUSIC spectrum -> transposed padded split output (b, t=a+1 in 362, f in 288)
// ---------------------------------------------------------------------------
__global__ __launch_bounds__(256) void music_kernel(
    const float4* __restrict__ svr, const float4* __restrict__ svi,
    const double* __restrict__ rp, u16* __restrict__ muhi, u16* __restrict__ mulo)
{
    __shared__ double P[32][16];
    __shared__ float T[32][33];
    int bid = blockIdx.x;
    int at = bid % 12; bid /= 12;
    int ft = bid % 9;
    int b = bid / 9;
    int f0 = ft * 32, a0 = at * 32;
    int tid = threadIdx.x;
    for (int i = tid; i < 32 * 16; i += 256) {
        int fi = i >> 4, j = i & 15;
        int f = f0 + fi;
        P[fi][j] = (f < 257) ? rp[((size_t)b * 257 + f) * 16 + j] : 0.0;
    }
    __syncthreads();
    int asub = tid & 31, fsub = tid >> 5;
    int a = a0 + asub;
    #pragma unroll
    for (int k2 = 0; k2 < 4; ++k2) {
        int fl = fsub + 8 * k2;
        int f = f0 + fl;
        float val = 0.f;
        if (a < 360 && f < 257) {
            float4 u = svr[((size_t)b * 257 + f) * 360 + a];
            float4 w = svi[((size_t)b * 257 + f) * 360 + a];
            const double* Pf = P[fl];
            double ua[4] = {u.x, u.y, u.z, u.w};
            double wa[4] = {w.x, w.y, w.z, w.w};
            double qa = 0.0, qb = 0.0;
            #pragma unroll
            for (int m = 0; m < 4; ++m)
                #pragma unroll
                for (int n = 0; n < 4; ++n) {
                    double pmn = Pf[m * 4 + n];
                    qa += pmn * ua[m] * ua[n];
                    qb += pmn * wa[m] * wa[n];
                }
            double den = qa - qb;
            val = (float)(1.0 / fmax(den, 1e-6));
        }
        T[asub][fl] = val;
    }
    __syncthreads();
    #pragma unroll
    for (int p = 0; p < 4; ++p) {
        int row = p * 8 + (tid >> 5);
        int fc = tid & 31;
        int a2 = a0 + row;
        if (a2 < 360) {
            float v = T[row][fc];
            size_t o = (((size_t)b * 362) + a2 + 1) * 288 + f0 + fc;
            u16 hh = f2bf(v);
            muhi[o] = hh;
            mulo[o] = f2bf(v - bf2f(hh));
        }
    }
}

// ---------------------------------------------------------------------------
// attention partial t-sums then finish (mean -> MLP -> sigmoid)
// ---------------------------------------------------------------------------
__global__ __launch_bounds__(256) void attn_partial(const float* __restrict__ sp2, float* __restrict__ part)
{
    int bid = blockIdx.x;
    int ch = bid % 6;
    int b = bid / 6;
    int t0 = ch * 60;
    for (int f = threadIdx.x; f < 257; f += 256) {
        float s = 0.f;
        for (int t = 0; t < 60; ++t) s += sp2[((size_t)b * 360 + t0 + t) * 257 + f];
        part[((size_t)b * 6 + ch) * 257 + f] = s;
    }
}

__global__ __launch_bounds__(256) void attn_finish(
    const float* __restrict__ part, const float* __restrict__ w1,
    const float* __restrict__ w2, float* __restrict__ att)
{
    __shared__ float ys[257];
    __shared__ float hs[16];
    int b = blockIdx.x;
    int tid = threadIdx.x;
    for (int f = tid; f < 257; f += 256) {
        float s = 0.f;
        #pragma unroll
        for (int c = 0; c < 6; ++c) s += part[((size_t)b * 6 + c) * 257 + f];
        ys[f] = s * (1.0f / 360.0f);
    }
    __syncthreads();
    if (tid < 16) {
        float h = 0.f;
        for (int c = 0; c < 257; ++c) h = fmaf(ys[c], w1[(size_t)tid * 257 + c], h);
        hs[tid] = fmaxf(h, 0.f);
    }
    __syncthreads();
    for (int o = tid; o < 257; o += 256) {
        float a = 0.f;
        #pragma unroll
        for (int j = 0; j < 16; ++j) a = fmaf(hs[j], w2[(size_t)o * 16 + j], a);
        att[(size_t)b * 257 + o] = 1.0f / (1.0f + expf(-a));
    }
}

// ---------------------------------------------------------------------------
// conv1d 257->1 over att-weighted sp2(b,t,f), sigmoid -> outS (b,360)
// ---------------------------------------------------------------------------
__global__ __launch_bounds__(256) void convs1_kernel(
    const float* __restrict__ sp2, const float* __restrict__ att,
    const float* __restrict__ w, const float* __restrict__ bb,
    float* __restrict__ outS)
{
    int bid = blockIdx.x;
    int tt = bid % 90;
    int b = bid / 90;
    int wv = threadIdx.x >> 6, l = threadIdx.x & 63;
    int t = tt * 4 + wv;
    float s = 0.f;
    for (int f = l; f < 257; f += 64) {
        float av = att[(size_t)b * 257 + f];
        float w0 = w[f * 3] * av, w1 = w[f * 3 + 1] * av, w2 = w[f * 3 + 2] * av;
        const float* col = sp2 + (size_t)b * 360 * 257 + f;
        if (t > 0)   s = fmaf(w0, col[(size_t)(t - 1) * 257], s);
        s = fmaf(w1, col[(size_t)t * 257], s);
        if (t < 359) s = fmaf(w2, col[(size_t)(t + 1) * 257], s);
    }
    #pragma unroll
    for (int off = 32; off > 0; off >>= 1) s += __shfl_down(s, off, 64);
    if (l == 0) outS[(size_t)b * 360 + t] = 1.0f / (1.0f + expf(-(s + bb[0])));
}

// ---------------------------------------------------------------------------
// top-5 soft-argmax, wave-parallel (strict >, index asc tie-break)
// ---------------------------------------------------------------------------
__global__ __launch_bounds__(64) void doa_kernel(const float* __restrict__ spec, float* __restrict__ doa)
{
    int b = blockIdx.x;
    int l = threadIdx.x;
    const float* s = spec + (size_t)b * NANG;
    float v[6];
    #pragma unroll
    for (int j = 0; j < 6; ++j) {
        int idx = l + 64 * j;
        v[j] = (idx < NANG) ? s[idx] : -3.4e38f;
    }
    float wvv[5]; int wii[5];
    #pragma unroll
    for (int k = 0; k < 5; ++k) {
        float bv = v[0]; int bj = 0;
        #pragma unroll
        for (int j = 1; j < 6; ++j)
            if (v[j] > bv) { bv = v[j]; bj = j; }
        int bi = l + 64 * bj;
        #pragma unroll
        for (int off = 1; off < 64; off <<= 1) {
            float ov = __shfl_xor(bv, off, 64);
            int oi = __shfl_xor(bi, off, 64);
            if (ov > bv || (ov == bv && oi < bi)) { bv = ov; bi = oi; }
        }
        wvv[k] = bv; wii[k] = bi;
        if ((bi & 63) == l) {
            int j = bi >> 6;
            #pragma unroll
            for (int jj = 0; jj < 6; ++jj)
                if (jj == j) v[jj] = -3.4e38f;
        }
    }
    if (l == 0) {
        float m = wvv[0];
        float wsum = 0.f, asum = 0.f;
        #pragma unroll
        for (int k = 0; k < 5; ++k) {
            float e = expf(20.0f * (wvv[k] - m));
            wsum += e;
            asum += e * (float)wii[k];
        }
        doa[b] = asum / wsum;
    }
}

// ---------------------------------------------------------------------------
extern "C" void kernel_launch(void* const* d_in, const int* in_sizes, int n_in,
                              void* d_out, int out_size, void* d_ws, size_t ws_size,
                              hipStream_t stream)
{
    const float* X    = (const float*)d_in[0];
    const float* svr  = (const float*)d_in[1];
    const float* svi  = (const float*)d_in[2];
    const float* c1w  = (const float*)d_in[4];
    const float* c2w  = (const float*)d_in[5];
    const float* c3w  = (const float*)d_in[6];
    const float* c4w  = (const float*)d_in[7];
    const float* fcw  = (const float*)d_in[8];
    const float* fcb  = (const float*)d_in[9];
    const float* s2w  = (const float*)d_in[10];
    const float* s2b  = (const float*)d_in[11];
    const float* s1w  = (const float*)d_in[12];
    const float* s1b  = (const float*)d_in[13];
    const float* caw1 = (const float*)d_in[14];
    const float* caw2 = (const float*)d_in[15];
    const float* bn1g = (const float*)d_in[16]; const float* bn1b = (const float*)d_in[17];
    const float* bn1m = (const float*)d_in[18]; const float* bn1v = (const float*)d_in[19];
    const float* bn2g = (const float*)d_in[20]; const float* bn2b = (const float*)d_in[21];
    const float* bn2m = (const float*)d_in[22]; const float* bn2v = (const float*)d_in[23];
    const float* bn3g = (const float*)d_in[24]; const float* bn3b = (const float*)d_in[25];
    const float* bn3m = (const float*)d_in[26]; const float* bn3v = (const float*)d_in[27];
    const float* bn4g = (const float*)d_in[28]; const float* bn4b = (const float*)d_in[29];
    const float* bn4m = (const float*)d_in[30]; const float* bn4v = (const float*)d_in[31];

    char* wsb = (char*)d_ws;
    // region A (time-disjoint: xp -> c3 -> mu)
    u16* xp_hi = (u16*)(wsb + 0);
    u16* xp_lo = (u16*)(wsb + 17305600);
    u16* c3_hi = (u16*)(wsb + 0);
    u16* c3_lo = (u16*)(wsb + 9469952);
    u16* mu_hi = (u16*)(wsb + 0);
    u16* mu_lo = (u16*)(wsb + 13344768);
    // region B (c2 -> {z, zfc, rp, sp2, part, att})
    const size_t Bb = 34611200;
    u16*   c2_hi = (u16*)(wsb + Bb);
    u16*   c2_lo = (u16*)(wsb + Bb + 35684352);
    float*  zbuf = (float*)(wsb + Bb);
    float*  zfc  = (float*)(wsb + Bb + 4210688);
    double* rp   = (double*)(wsb + Bb + 6316032);
    float*  sp2  = (float*)(wsb + Bb + 8421376);
    float*  part = (float*)(wsb + Bb + 32106496);
    float*  att  = (float*)(wsb + Bb + 32501248);
    // region C (persistent small)
    const size_t Cb = Bb + 71368704;
    u16* c4_hi = (u16*)(wsb + Cb);
    u16* c4_lo = (u16*)(wsb + Cb + 2654208);
    u16* bp1 = (u16*)(wsb + Cb + 5308416);
    u16* bp2 = (u16*)(wsb + Cb + 5382144);
    u16* bp3 = (u16*)(wsb + Cb + 5529600);
    u16* bp4 = (u16*)(wsb + Cb + 5677056);
    u16* bp5 = (u16*)(wsb + Cb + 6414336);
    float* bns = (float*)(wsb + Cb + 7409664);

    float* outD = (float*)d_out;
    float* outS = (float*)d_out + 64;

    // --- prep ---
    bnprep<<<4, 256, 0, stream>>>(bn1g, bn1b, bn1m, bn1v, bn2g, bn2b, bn2m, bn2v,
                                  bn3g, bn3b, bn3m, bn3v, bn4g, bn4b, bn4m, bn4v, bns);
    bpack1<<<6, 256, 0, stream>>>(c1w, bp1);
    bpack<<<36, 256, 0, stream>>>(c2w, bp2, 64, 64, 9, 2, 4);
    bpack<<<36, 256, 0, stream>>>(c3w, bp3, 64, 64, 9, 2, 4);
    bpack<<<180, 256, 0, stream>>>(c4w, bp4, 64, 257, 9, 2, 20);
    bpack<<<243, 256, 0, stream>>>(s2w, bp5, 257, 257, 3, 9, 18);
    xpack_kernel<<<64 * 130, 256, 0, stream>>>(X, xp_hi, xp_lo);
    zpad<<<4161, 256, 0, stream>>>(c2_hi, c2_lo, 64, 66, 66, 64, 1);
    zpad<<<1088, 256, 0, stream>>>(c4_hi, c4_lo, 64, 18, 18, 64, 1);

    // --- conv1 ---
    conv_c1<<<64 * 64, 256, 0, stream>>>(xp_hi, xp_lo, bp1, bns, bns + 512, c2_hi, c2_lo);
    zpad<<<2112, 256, 0, stream>>>(c3_hi, c3_lo, 64, 34, 34, 64, 1);  // A region free now
    // --- conv2 ---
    conv_gemm<64, 64, 64, 2, 4, 2, 0, 4>
        <<<dim3(64 * 32, 1), 256, 0, stream>>>(c2_hi, c2_lo, bp2, bns + 1024, bns + 1536, c3_hi, c3_lo, nullptr);
    // --- conv3 ---
    conv_gemm<32, 32, 64, 4, 4, 2, 0, 4>
        <<<dim3(64 * 8, 1), 256, 0, stream>>>(c3_hi, c3_lo, bp3, bns + 2048, bns + 2560, c4_hi, c4_lo, nullptr);
    zpad<<<144, 256, 0, stream>>>(mu_hi, mu_lo, 64, 362, 1, 288, 0);  // A region free now
    // --- conv4 -> z f32 (b,8,8,257) ---
    conv_gemm<16, 16, 257, 8, 4, 2, 1, 20>
        <<<dim3(64 * 2, 5), 256, 0, stream>>>(c4_hi, c4_lo, bp4, bns + 3072, bns + 3584, nullptr, nullptr, zbuf);

    fc_kernel<<<64 * 33, 256, 0, stream>>>(zbuf, fcw, fcb, zfc);
    eigh_kernel<<<NFB, 64, 0, stream>>>(zfc, rp);
    music_kernel<<<64 * 108, 256, 0, stream>>>((const float4*)svr, (const float4*)svi, rp, mu_hi, mu_lo);
    // --- convs2 ---
    convs2_gemm<<<dim3(64, 6), 512, 0, stream>>>(mu_hi, mu_lo, bp5, s2b, sp2);

    attn_partial<<<64 * 6, 256, 0, stream>>>(sp2, part);
    attn_finish<<<64, 256, 0, stream>>>(part, caw1, caw2, att);
    convs1_kernel<<<64 * 90, 256, 0, stream>>>(sp2, att, s1w, s1b, outS);
    doa_kernel<<<64, 64, 0, stream>>>(outS, outD);
}